// Round 5
// baseline (1204.096 us; speedup 1.0000x reference)
//
#include <hip/hip_runtime.h>
#include <hip/hip_bf16.h>
#include <math.h>

#define N_NODES 40000
#define N_EDGES 640000
#define DIM     128
#define HEADS   8
#define DHEAD   16
#define LAYERS  3
#define IN_DIM  64
#define FF_DIM  218
#define BN_EPS  1e-5f
#define NEG_SLOPE 0.2f

typedef __attribute__((ext_vector_type(8))) short  bhalf8;
typedef __attribute__((ext_vector_type(4))) float  floatx4;
typedef __attribute__((ext_vector_type(4))) int    intx4;

// fp32 -> bf16 (RNE), two packed into one dword (lo = even k, hi = odd k)
__device__ __forceinline__ unsigned bfpack2(float a, float b) {
    unsigned ua = __float_as_uint(a);
    ua = ua + 0x7FFFu + ((ua >> 16) & 1u);
    unsigned ub = __float_as_uint(b);
    ub = ub + 0x7FFFu + ((ub >> 16) & 1u);
    return (ua >> 16) | (ub & 0xFFFF0000u);
}
__device__ __forceinline__ unsigned short bf16of(float a) {
    unsigned ua = __float_as_uint(a);
    ua = ua + 0x7FFFu + ((ua >> 16) & 1u);
    return (unsigned short)(ua >> 16);
}
__device__ __forceinline__ float bf2f(unsigned short u) {
    unsigned v = ((unsigned)u) << 16;
    return __uint_as_float(v);
}

// ---------------------------------------------------------------- CSR build
__global__ void hist_kernel(const int* __restrict__ dst, int* __restrict__ counts) {
    int e = blockIdx.x * blockDim.x + threadIdx.x;
    if (e < N_EDGES) atomicAdd(&counts[dst[e]], 1);
}

__global__ void scan_kernel(const int* __restrict__ counts, int* __restrict__ indptr, int n) {
    __shared__ int temp[1024];
    __shared__ int carry;
    int tid = threadIdx.x;
    if (tid == 0) carry = 0;
    __syncthreads();
    for (int base = 0; base < n; base += 1024) {
        int v = (base + tid < n) ? counts[base + tid] : 0;
        temp[tid] = v;
        __syncthreads();
        for (int offs = 1; offs < 1024; offs <<= 1) {
            int t = (tid >= offs) ? temp[tid - offs] : 0;
            __syncthreads();
            temp[tid] += t;
            __syncthreads();
        }
        int incl = temp[tid];
        if (base + tid < n) indptr[base + tid] = carry + incl - v;
        __syncthreads();
        if (tid == 0) carry += temp[1023];
        __syncthreads();
    }
    if (tid == 0) indptr[n] = carry;
}

// CSR scatter: record src and dst node per CSR slot
__global__ void scatter_kernel(const int* __restrict__ src, const int* __restrict__ dst,
                               int* __restrict__ cursor,
                               int* __restrict__ srcs_csr, int* __restrict__ dsts_csr) {
    int e = blockIdx.x * blockDim.x + threadIdx.x;
    if (e < N_EDGES) {
        int d = dst[e];
        int pos = atomicAdd(&cursor[d], 1);
        srcs_csr[pos] = src[e];
        dsts_csr[pos] = d;
    }
}

// ---------------------------------------------------------------- B-resident bf16 MFMA GEMM
// C[M,N] = A[M,K] @ B[K,N] (+bias) (+res) (relu?)  fp32 in, fp32 or bf16 out.
// B staged per 128-K chunk into LDS (bf16, [kblock][col][4dw] layout); K-loop has
// NO barriers: A streamed global->reg per wave (2 m-tiles x 16 rows), B via ds_read_b128.
template<int NT>   // number of 16-col tiles; N <= NT*16
__global__ __launch_bounds__(256) void gemm_bres_kernel(
    const float* __restrict__ A, int lda,
    const float* __restrict__ B, int ldb,
    const float* __restrict__ bias,
    const float* __restrict__ res, int ldres,
    float* __restrict__ C, unsigned short* __restrict__ Cbf, int ldc,
    int M, int Nact, int K, int relu)
{
    constexpr int NCOLS = NT * 16;
    __shared__ unsigned Bs[16 * NCOLS * 4];   // 16 kblocks x NCOLS cols x 4 dwords (8 bf16)

    int tid = threadIdx.x;
    int wave = tid >> 6, lane = tid & 63;
    int q = lane >> 4, tl = lane & 15;
    int row0 = blockIdx.x * 128;

    // A rows this wave loads (m = lane&15 in A-frag layout)
    int rt0 = row0 + wave * 32 + tl;
    int rt1 = rt0 + 16;
    bool v0 = rt0 < M, v1 = rt1 < M;
    const float* a0 = A + (size_t)rt0 * lda;
    const float* a1 = A + (size_t)rt1 * lda;

    floatx4 acc[2][NT] = {};

    for (int kbase = 0; kbase < K; kbase += 128) {
        int kc  = min(128, K - kbase);
        int kcc = (kc + 31) & ~31;            // k0 loop bound (B zero-padded to here)
        int items = (kcc >> 3) * NCOLS;

        if (kbase) __syncthreads();
        // ---- stage B chunk: item = (kblock, col); coalesced global reads per k-row
        for (int idx = tid; idx < items; idx += 256) {
            int n  = idx % NCOLS;
            int kb = idx / NCOLS;
            int gk = kbase + kb * 8;
            unsigned pk[4];
            #pragma unroll
            for (int jj = 0; jj < 4; jj++) {
                int k2 = gk + 2 * jj;
                float f0 = (n < Nact && k2     < K) ? B[(size_t)k2 * ldb + n]       : 0.f;
                float f1 = (n < Nact && k2 + 1 < K) ? B[(size_t)(k2 + 1) * ldb + n] : 0.f;
                pk[jj] = bfpack2(f0, f1);
            }
            *(intx4*)&Bs[((size_t)kb * NCOLS + n) * 4] =
                intx4{(int)pk[0], (int)pk[1], (int)pk[2], (int)pk[3]};
        }
        __syncthreads();

        // ---- barrier-free K loop
        for (int k0 = 0; k0 < kcc; k0 += 32) {
            bhalf8 bf[NT];
            #pragma unroll
            for (int j = 0; j < NT; j++)
                bf[j] = *(const bhalf8*)&Bs[(((k0 >> 3) + q) * NCOLS + j * 16 + tl) * 4];

            int gk = kbase + k0 + q * 8;
            bhalf8 af0, af1;
            {
                floatx4 x0 = {}, x1 = {};
                if (v0) { x0 = *(const floatx4*)(a0 + gk); x1 = *(const floatx4*)(a0 + gk + 4); }
                intx4 t = intx4{(int)bfpack2(x0[0], x0[1]), (int)bfpack2(x0[2], x0[3]),
                                (int)bfpack2(x1[0], x1[1]), (int)bfpack2(x1[2], x1[3])};
                af0 = *(bhalf8*)&t;
            }
            {
                floatx4 x0 = {}, x1 = {};
                if (v1) { x0 = *(const floatx4*)(a1 + gk); x1 = *(const floatx4*)(a1 + gk + 4); }
                intx4 t = intx4{(int)bfpack2(x0[0], x0[1]), (int)bfpack2(x0[2], x0[3]),
                                (int)bfpack2(x1[0], x1[1]), (int)bfpack2(x1[2], x1[3])};
                af1 = *(bhalf8*)&t;
            }
            #pragma unroll
            for (int j = 0; j < NT; j++) {
                acc[0][j] = __builtin_amdgcn_mfma_f32_16x16x32_bf16(af0, bf[j], acc[0][j], 0, 0, 0);
                acc[1][j] = __builtin_amdgcn_mfma_f32_16x16x32_bf16(af1, bf[j], acc[1][j], 0, 0, 0);
            }
        }
    }

    // ---- epilogue: C/D layout col=lane&15, row=quad*4+reg
    #pragma unroll
    for (int j = 0; j < NT; j++) {
        int c = j * 16 + tl;
        if (c >= Nact) continue;
        float bv = bias ? bias[c] : 0.f;
        #pragma unroll
        for (int t = 0; t < 2; t++) {
            #pragma unroll
            for (int reg = 0; reg < 4; reg++) {
                int r = row0 + wave * 32 + t * 16 + q * 4 + reg;
                if (r >= M) continue;
                float v = acc[t][j][reg] + bv;
                if (res)  v += res[(size_t)r * ldres + c];
                if (relu) v = fmaxf(v, 0.f);
                if (Cbf) Cbf[(size_t)r * ldc + c] = bf16of(v);
                else     C  [(size_t)r * ldc + c] = v;
            }
        }
    }
}

// ---------------------------------------------------------------- GAT pieces
__global__ void eler_kernel(const unsigned short* __restrict__ feat,
                            const float* __restrict__ al, const float* __restrict__ ar,
                            float* __restrict__ el, float* __restrict__ er) {
    int i = blockIdx.x * blockDim.x + threadIdx.x;
    if (i >= N_NODES * HEADS) return;
    int n = i >> 3, h = i & 7;
    const unsigned short* f = feat + (size_t)n * DIM + h * DHEAD;
    float sl = 0.f, sr = 0.f;
    #pragma unroll
    for (int d = 0; d < DHEAD; d++) {
        float fv = bf2f(f[d]);
        sl = fmaf(fv, al[h * DHEAD + d], sl);
        sr = fmaf(fv, ar[h * DHEAD + d], sr);
    }
    el[i] = sl;
    er[i] = sr;
}

// CSR-ordered: one thread per CSR slot, all 8 heads; coalesced ebuf writes
__global__ void edge_exp_kernel(const int* __restrict__ srcs_csr,
                                const int* __restrict__ dsts_csr,
                                const float* __restrict__ el, const float* __restrict__ er,
                                float* __restrict__ ebuf_csr) {
    int i = blockIdx.x * blockDim.x + threadIdx.x;
    if (i >= N_EDGES) return;
    int s = srcs_csr[i], d = dsts_csr[i];
    floatx4 l0 = *(const floatx4*)&el[(size_t)s * 8];
    floatx4 l1 = *(const floatx4*)&el[(size_t)s * 8 + 4];
    floatx4 r0 = *(const floatx4*)&er[(size_t)d * 8];
    floatx4 r1 = *(const floatx4*)&er[(size_t)d * 8 + 4];
    floatx4 o0, o1;
    #pragma unroll
    for (int h = 0; h < 4; h++) {
        float v = l0[h] + r0[h];
        v = v > 0.f ? v : NEG_SLOPE * v;
        o0[h] = expf(v);
        float w = l1[h] + r1[h];
        w = w > 0.f ? w : NEG_SLOPE * w;
        o1[h] = expf(w);
    }
    *(floatx4*)&ebuf_csr[(size_t)i * 8]     = o0;
    *(floatx4*)&ebuf_csr[(size_t)i * 8 + 4] = o1;
}

// per-dst-node: contiguous alpha + src reads, single gather level on bf16 feat
__global__ __launch_bounds__(256) void gat_aggregate_kernel(
    const unsigned short* __restrict__ feat, const float* __restrict__ ebuf_csr,
    const int* __restrict__ indptr, const int* __restrict__ srcs_csr,
    const float* __restrict__ h_in, int ldh,
    const float* __restrict__ bias,
    float* __restrict__ outp)
{
    int n = blockIdx.x;
    int t = threadIdx.x;
    __shared__ float inv_s[HEADS];
    __shared__ float red[256];
    int beg = indptr[n], end = indptr[n + 1];

    // phase 1: denominator per head, 32 edges x 8 heads parallel (contiguous reads)
    {
        int j = t >> 3, h = t & 7;
        float s = 0.f;
        for (int i = beg + j; i < end; i += 32)
            s += ebuf_csr[(size_t)i * HEADS + h];
        red[t] = s;
    }
    __syncthreads();
    if (t < HEADS) {
        float s = 0.f;
        #pragma unroll
        for (int j = 0; j < 32; j++) s += red[j * 8 + t];
        inv_s[t] = (s > 0.f) ? 1.f / s : 0.f;
    }
    __syncthreads();

    // phase 2: aggregate, 2 groups x 4-way unroll = 8 feat gathers in flight
    int p = t >> 7;          // 0/1 edge group
    int d = t & 127;         // feature dim
    int hh = d >> 4;         // head of this dim
    float inv = inv_s[hh];
    float acc = 0.f;
    int i = beg + p;
    for (; i + 6 < end; i += 8) {
        int s0 = srcs_csr[i],     s1 = srcs_csr[i + 2];
        int s2 = srcs_csr[i + 4], s3 = srcs_csr[i + 6];
        float a0 = ebuf_csr[(size_t)(i)     * HEADS + hh];
        float a1 = ebuf_csr[(size_t)(i + 2) * HEADS + hh];
        float a2 = ebuf_csr[(size_t)(i + 4) * HEADS + hh];
        float a3 = ebuf_csr[(size_t)(i + 6) * HEADS + hh];
        float f0 = bf2f(feat[(size_t)s0 * DIM + d]);
        float f1 = bf2f(feat[(size_t)s1 * DIM + d]);
        float f2 = bf2f(feat[(size_t)s2 * DIM + d]);
        float f3 = bf2f(feat[(size_t)s3 * DIM + d]);
        acc = fmaf(a0, f0, acc);
        acc = fmaf(a1, f1, acc);
        acc = fmaf(a2, f2, acc);
        acc = fmaf(a3, f3, acc);
    }
    for (; i < end; i += 2) {
        int s0 = srcs_csr[i];
        acc = fmaf(ebuf_csr[(size_t)i * HEADS + hh],
                   bf2f(feat[(size_t)s0 * DIM + d]), acc);
    }
    acc *= inv;
    __syncthreads();
    red[t] = acc;
    __syncthreads();
    if (t < 128) {
        float v = red[d] + red[128 + d];
        outp[(size_t)n * DIM + d] = h_in[(size_t)n * ldh + d] + v + bias[d];
    }
}

// ---------------------------------------------------------------- BatchNorm
__global__ __launch_bounds__(128) void bn_stats_kernel(const float* __restrict__ x, int ldx,
                                                       int M, float* __restrict__ stats) {
    int c = threadIdx.x;
    int r0 = blockIdx.x * 128;
    int r1 = min(r0 + 128, M);
    float s = 0.f, sq = 0.f;
    for (int r = r0; r < r1; r++) {
        float v = x[(size_t)r * ldx + c];
        s += v;
        sq = fmaf(v, v, sq);
    }
    atomicAdd(&stats[c], s);
    atomicAdd(&stats[DIM + c], sq);
}

__global__ void bn_apply_kernel(const float* __restrict__ x, int ldin,
                                float* __restrict__ y, int ldout,
                                const float* __restrict__ g, const float* __restrict__ b,
                                const float* __restrict__ stats, int M) {
    int i = blockIdx.x * blockDim.x + threadIdx.x;
    if (i >= M * DIM) return;
    int r = i >> 7, c = i & 127;
    float mu  = stats[c] * (1.f / N_NODES);
    float var = stats[DIM + c] * (1.f / N_NODES) - mu * mu;
    float v = x[(size_t)r * ldin + c];
    y[(size_t)r * ldout + c] = fmaf(g[c] * rsqrtf(var + BN_EPS), v - mu, b[c]);
}

// ---------------------------------------------------------------- decision head
__global__ __launch_bounds__(256) void decide_kernel(
    const float* __restrict__ z, const float* __restrict__ stats,
    const float* __restrict__ g, const float* __restrict__ b,
    const float* __restrict__ W2, float* __restrict__ outp, int M)
{
    int wid = threadIdx.x >> 6, lane = threadIdx.x & 63;
    int n = blockIdx.x * 4 + wid;
    if (n >= M) return;
    float acc = 0.f;
    for (int c = lane; c < DIM; c += 64) {
        float mu  = stats[c] * (1.f / N_NODES);
        float var = stats[DIM + c] * (1.f / N_NODES) - mu * mu;
        float v = fmaf(g[c] * rsqrtf(var + BN_EPS), z[(size_t)n * DIM + c] - mu, b[c]);
        v = fmaxf(v, 0.f);
        acc = fmaf(v, W2[c], acc);
    }
    #pragma unroll
    for (int offs = 32; offs > 0; offs >>= 1)
        acc += __shfl_down(acc, offs);
    if (lane == 0) outp[n] = acc;
}

// ---------------------------------------------------------------- launch
extern "C" void kernel_launch(void* const* d_in, const int* in_sizes, int n_in,
                              void* d_out, int out_size, void* d_ws, size_t ws_size,
                              hipStream_t stream)
{
    const float* x      = (const float*)d_in[0];
    const int*   src    = (const int*)  d_in[1];
    const int*   dst    = (const int*)  d_in[2];
    const float* W_emb  = (const float*)d_in[3];
    const float* b_emb  = (const float*)d_in[4];
    const float* gat_W  = (const float*)d_in[5];
    const float* attn_l = (const float*)d_in[6];
    const float* attn_r = (const float*)d_in[7];
    const float* gat_b  = (const float*)d_in[8];
    const float* bn1_g  = (const float*)d_in[9];
    const float* bn1_b  = (const float*)d_in[10];
    const float* ff_W1  = (const float*)d_in[11];
    const float* ff_b1  = (const float*)d_in[12];
    const float* ff_W2  = (const float*)d_in[13];
    const float* ff_b2  = (const float*)d_in[14];
    const float* bn2_g  = (const float*)d_in[15];
    const float* bn2_b  = (const float*)d_in[16];
    const float* dec_W1 = (const float*)d_in[17];
    const float* dec_bn_g = (const float*)d_in[18];
    const float* dec_bn_b = (const float*)d_in[19];
    const float* dec_W2 = (const float*)d_in[20];
    float* outp = (float*)d_out;

    char* ws = (char*)d_ws;
    size_t off = 0;
    auto alloc = [&](size_t bytes) -> void* {
        void* p = ws + off;
        off += (bytes + 255) & ~(size_t)255;
        return p;
    };
    float* xs    = (float*)alloc((size_t)N_NODES * 512 * 4);
    float* z     = (float*)alloc((size_t)N_NODES * DIM * 4);
    unsigned short* featb = (unsigned short*)alloc((size_t)N_NODES * DIM * 2);
    float* el    = (float*)alloc((size_t)N_NODES * HEADS * 4);
    float* er    = (float*)alloc((size_t)N_NODES * HEADS * 4);
    float* ebuf  = (float*)alloc((size_t)N_EDGES * HEADS * 4);
    float* y1    = (float*)alloc((size_t)N_NODES * 224 * 4);   // ld=224 for aligned float4
    float* bt    = (float*)alloc((size_t)N_NODES * DIM * 4);
    float* stats = (float*)alloc(2 * DIM * 4);
    int*   counts= (int*)  alloc((size_t)N_NODES * 4);
    int*   indptr= (int*)  alloc((size_t)(N_NODES + 1) * 4);
    int*   cursor= (int*)  alloc((size_t)N_NODES * 4);
    int*   srcs_csr = (int*)alloc((size_t)N_EDGES * 4);
    int*   dsts_csr = (int*)alloc((size_t)N_EDGES * 4);
    (void)ws_size; (void)in_sizes; (void)n_in; (void)out_size;

    int gemm_grid = (N_NODES + 127) / 128;
    auto gemm128 = [&](const float* A, int lda, const float* B, int ldb,
                       const float* bias, const float* res, int ldres,
                       float* C, unsigned short* Cbf, int ldc, int K, int relu) {
        gemm_bres_kernel<8><<<gemm_grid, 256, 0, stream>>>(
            A, lda, B, ldb, bias, res, ldres, C, Cbf, ldc, N_NODES, 128, K, relu);
    };

    // ---- CSR build
    hipMemsetAsync(counts, 0, N_NODES * 4, stream);
    hist_kernel<<<(N_EDGES + 255) / 256, 256, 0, stream>>>(dst, counts);
    scan_kernel<<<1, 1024, 0, stream>>>(counts, indptr, N_NODES);
    hipMemcpyAsync(cursor, indptr, N_NODES * 4, hipMemcpyDeviceToDevice, stream);
    scatter_kernel<<<(N_EDGES + 255) / 256, 256, 0, stream>>>(src, dst, cursor, srcs_csr, dsts_csr);

    // ---- embed: xs[:,0:128] = x @ W_emb + b_emb
    gemm128(x, IN_DIM, W_emb, DIM, b_emb, nullptr, 0, xs, nullptr, 512, IN_DIM, 0);

    for (int l = 0; l < LAYERS; l++) {
        const float* h_cur = xs + (size_t)l * DIM;
        // feat (bf16 out)
        gemm128(h_cur, 512, gat_W + (size_t)l * DIM * DIM, DIM,
                nullptr, nullptr, 0, nullptr, featb, DIM, DIM, 0);
        eler_kernel<<<(N_NODES * HEADS + 255) / 256, 256, 0, stream>>>(
            featb, attn_l + l * DIM, attn_r + l * DIM, el, er);
        edge_exp_kernel<<<(N_EDGES + 255) / 256, 256, 0, stream>>>(
            srcs_csr, dsts_csr, el, er, ebuf);
        gat_aggregate_kernel<<<N_NODES, 256, 0, stream>>>(
            featb, ebuf, indptr, srcs_csr, h_cur, 512, gat_b + l * DIM, bt);
        // BN1
        hipMemsetAsync(stats, 0, 2 * DIM * 4, stream);
        bn_stats_kernel<<<(N_NODES + 127) / 128, 128, 0, stream>>>(bt, DIM, N_NODES, stats);
        bn_apply_kernel<<<(N_NODES * DIM + 255) / 256, 256, 0, stream>>>(
            bt, DIM, bt, DIM, bn1_g + l * DIM, bn1_b + l * DIM, stats, N_NODES);
        // FFN1: y1 = relu(bt @ W1 + b1)  (N=218, NT=14, out ld 224)
        gemm_bres_kernel<14><<<gemm_grid, 256, 0, stream>>>(
            bt, DIM, ff_W1 + (size_t)l * DIM * FF_DIM, FF_DIM,
            ff_b1 + l * FF_DIM, nullptr, 0, y1, nullptr, 224,
            N_NODES, FF_DIM, DIM, 1);
        // FFN2: bt = y1 @ W2 + b2 + bt
        gemm128(y1, 224, ff_W2 + (size_t)l * FF_DIM * DIM, DIM,
                ff_b2 + l * DIM, bt, DIM, bt, nullptr, DIM, FF_DIM, 0);
        // BN2 -> xs[:, (l+1)*128...]
        hipMemsetAsync(stats, 0, 2 * DIM * 4, stream);
        bn_stats_kernel<<<(N_NODES + 127) / 128, 128, 0, stream>>>(bt, DIM, N_NODES, stats);
        bn_apply_kernel<<<(N_NODES * DIM + 255) / 256, 256, 0, stream>>>(
            bt, DIM, xs + (size_t)(l + 1) * DIM, 512,
            bn2_g + l * DIM, bn2_b + l * DIM, stats, N_NODES);
    }

    // ---- decision head: z = xs @ dec_W1 (K=512)
    gemm128(xs, 512, dec_W1, DIM, nullptr, nullptr, 0, z, nullptr, DIM, 4 * DIM, 0);
    hipMemsetAsync(stats, 0, 2 * DIM * 4, stream);
    bn_stats_kernel<<<(N_NODES + 127) / 128, 128, 0, stream>>>(z, DIM, N_NODES, stats);
    decide_kernel<<<(N_NODES + 3) / 4, 256, 0, stream>>>(
        z, stats, dec_bn_g, dec_bn_b, dec_W2, outp, N_NODES);
}

// Round 6
// 1130.845 us; speedup vs baseline: 1.0648x; 1.0648x over previous
//
#include <hip/hip_runtime.h>
#include <hip/hip_bf16.h>
#include <math.h>

#define N_NODES 40000
#define N_EDGES 640000
#define DIM     128
#define HEADS   8
#define DHEAD   16
#define LAYERS  3
#define IN_DIM  64
#define FF_DIM  218
#define BN_EPS  1e-5f
#define NEG_SLOPE 0.2f
#define INV_N   (1.f / N_NODES)

typedef __attribute__((ext_vector_type(8))) short  bhalf8;
typedef __attribute__((ext_vector_type(4))) float  floatx4;
typedef __attribute__((ext_vector_type(4))) int    intx4;

__device__ __forceinline__ unsigned bfpack2(float a, float b) {
    unsigned ua = __float_as_uint(a);
    ua = ua + 0x7FFFu + ((ua >> 16) & 1u);
    unsigned ub = __float_as_uint(b);
    ub = ub + 0x7FFFu + ((ub >> 16) & 1u);
    return (ua >> 16) | (ub & 0xFFFF0000u);
}
__device__ __forceinline__ unsigned short bf16of(float a) {
    unsigned ua = __float_as_uint(a);
    ua = ua + 0x7FFFu + ((ua >> 16) & 1u);
    return (unsigned short)(ua >> 16);
}
__device__ __forceinline__ float bf2f(unsigned short u) {
    unsigned v = ((unsigned)u) << 16;
    return __uint_as_float(v);
}

// ---------------------------------------------------------------- CSR build
__global__ void hist_kernel(const int* __restrict__ dst, int* __restrict__ counts) {
    int e = blockIdx.x * blockDim.x + threadIdx.x;
    if (e < N_EDGES) atomicAdd(&counts[dst[e]], 1);
}

// single-block chunked scan: 1024 threads x 40 elements each; writes indptr AND cursor
__global__ __launch_bounds__(1024) void scan_kernel(const int* __restrict__ counts,
                                                    int* __restrict__ indptr,
                                                    int* __restrict__ cursor, int n) {
    __shared__ int tsum[1024];
    const int CH = 40;
    int tid = threadIdx.x;
    int base = tid * CH;
    int loc[CH];
    int s = 0;
    #pragma unroll
    for (int i = 0; i < CH; i++) {
        int idx = base + i;
        int v = (idx < n) ? counts[idx] : 0;
        loc[i] = s;
        s += v;
    }
    tsum[tid] = s;
    __syncthreads();
    for (int offs = 1; offs < 1024; offs <<= 1) {
        int t = (tid >= offs) ? tsum[tid - offs] : 0;
        __syncthreads();
        tsum[tid] += t;
        __syncthreads();
    }
    int carry = (tid > 0) ? tsum[tid - 1] : 0;
    #pragma unroll
    for (int i = 0; i < CH; i++) {
        int idx = base + i;
        if (idx < n) {
            int v = carry + loc[i];
            indptr[idx] = v;
            cursor[idx] = v;
        }
    }
    if (tid == 1023) indptr[n] = tsum[1023];
}

__global__ void scatter_kernel(const int* __restrict__ src, const int* __restrict__ dst,
                               int* __restrict__ cursor,
                               int* __restrict__ srcs_csr, int* __restrict__ dsts_csr) {
    int e = blockIdx.x * blockDim.x + threadIdx.x;
    if (e < N_EDGES) {
        int d = dst[e];
        int pos = atomicAdd(&cursor[d], 1);
        srcs_csr[pos] = src[e];
        dsts_csr[pos] = d;
    }
}

// ---------------------------------------------------------------- fused B-resident bf16 MFMA GEMM
// C = affA(A) @ B (+bias) (+BN(res)) (relu?); optional bf16 out; optional column-stats epilogue.
// aff_mode: 0 none; 1 simple (a_stats=[sum128][sumsq128], a_g/a_b len K=128); 2 dec512
// (K=512: cols 0..127 identity, block l>=1 uses a_stats+(l-1)*256, a_g/a_b+(l-1)*128).
template<int NT, bool ABF16>
__global__ __launch_bounds__(256) void gemm_bres_kernel(
    const float* __restrict__ A, const unsigned short* __restrict__ Abf, int lda,
    const float* __restrict__ B, int ldb,
    const float* __restrict__ bias,
    const float* __restrict__ res, int ldres,
    const float* __restrict__ res_stats, const float* __restrict__ res_g,
    const float* __restrict__ res_b,
    float* __restrict__ C, unsigned short* __restrict__ Cbf, int ldc,
    float* __restrict__ out_stats,
    int M, int Nact, int K, int relu,
    int aff_mode, const float* __restrict__ a_stats,
    const float* __restrict__ a_g, const float* __restrict__ a_b)
{
    constexpr int NCOLS = NT * 16;
    __shared__ unsigned Bs[16 * NCOLS * 4];
    __shared__ float sc_s[512];
    __shared__ float sh_s[512];

    int tid = threadIdx.x;
    int wave = tid >> 6, lane = tid & 63;
    int q = lane >> 4, tl = lane & 15;
    int row0 = blockIdx.x * 128;

    int rt0 = row0 + wave * 32 + tl;
    int rt1 = rt0 + 16;
    bool v0 = rt0 < M, v1 = rt1 < M;
    const float* a0 = A ? A + (size_t)rt0 * lda : nullptr;
    const float* a1 = A ? A + (size_t)rt1 * lda : nullptr;
    const unsigned short* a0b = Abf ? Abf + (size_t)rt0 * lda : nullptr;
    const unsigned short* a1b = Abf ? Abf + (size_t)rt1 * lda : nullptr;

    // affine preamble (before first barrier)
    if (aff_mode) {
        for (int idx = tid; idx < K; idx += 256) {
            float scv = 1.f, shv = 0.f;
            if (aff_mode == 1) {
                float mu = a_stats[idx] * INV_N;
                float var = a_stats[128 + idx] * INV_N - mu * mu;
                scv = a_g[idx] * rsqrtf(var + BN_EPS);
                shv = a_b[idx] - mu * scv;
            } else {
                int l = idx >> 7;
                if (l > 0) {
                    int c = idx & 127;
                    const float* st = a_stats + (l - 1) * 256;
                    float mu = st[c] * INV_N;
                    float var = st[128 + c] * INV_N - mu * mu;
                    scv = a_g[(l - 1) * 128 + c] * rsqrtf(var + BN_EPS);
                    shv = a_b[(l - 1) * 128 + c] - mu * scv;
                }
            }
            sc_s[idx] = scv;
            sh_s[idx] = shv;
        }
    }

    floatx4 acc[2][NT] = {};

    for (int kbase = 0; kbase < K; kbase += 128) {
        int kc  = min(128, K - kbase);
        int kcc = (kc + 31) & ~31;
        int items = (kcc >> 3) * NCOLS;

        if (kbase) __syncthreads();
        for (int idx = tid; idx < items; idx += 256) {
            int n  = idx % NCOLS;
            int kb = idx / NCOLS;
            int gk = kbase + kb * 8;
            unsigned pk[4];
            #pragma unroll
            for (int jj = 0; jj < 4; jj++) {
                int k2 = gk + 2 * jj;
                float f0 = (n < Nact && k2     < K) ? B[(size_t)k2 * ldb + n]       : 0.f;
                float f1 = (n < Nact && k2 + 1 < K) ? B[(size_t)(k2 + 1) * ldb + n] : 0.f;
                pk[jj] = bfpack2(f0, f1);
            }
            *(intx4*)&Bs[((size_t)kb * NCOLS + n) * 4] =
                intx4{(int)pk[0], (int)pk[1], (int)pk[2], (int)pk[3]};
        }
        __syncthreads();

        for (int k0 = 0; k0 < kcc; k0 += 32) {
            bhalf8 bf[NT];
            #pragma unroll
            for (int j = 0; j < NT; j++)
                bf[j] = *(const bhalf8*)&Bs[(((k0 >> 3) + q) * NCOLS + j * 16 + tl) * 4];

            int gk = kbase + k0 + q * 8;
            bhalf8 af0 = {}, af1 = {};
            if constexpr (ABF16) {
                if (v0) af0 = *(const bhalf8*)(a0b + gk);
                if (v1) af1 = *(const bhalf8*)(a1b + gk);
            } else {
                floatx4 sc0, sc1, sh0, sh1;
                if (aff_mode) {
                    sc0 = *(floatx4*)&sc_s[gk]; sc1 = *(floatx4*)&sc_s[gk + 4];
                    sh0 = *(floatx4*)&sh_s[gk]; sh1 = *(floatx4*)&sh_s[gk + 4];
                }
                {
                    floatx4 x0 = {}, x1 = {};
                    if (v0) { x0 = *(const floatx4*)(a0 + gk); x1 = *(const floatx4*)(a0 + gk + 4); }
                    if (aff_mode) {
                        #pragma unroll
                        for (int jj = 0; jj < 4; jj++) {
                            x0[jj] = fmaf(sc0[jj], x0[jj], sh0[jj]);
                            x1[jj] = fmaf(sc1[jj], x1[jj], sh1[jj]);
                        }
                    }
                    intx4 t = intx4{(int)bfpack2(x0[0], x0[1]), (int)bfpack2(x0[2], x0[3]),
                                    (int)bfpack2(x1[0], x1[1]), (int)bfpack2(x1[2], x1[3])};
                    af0 = *(bhalf8*)&t;
                }
                {
                    floatx4 x0 = {}, x1 = {};
                    if (v1) { x0 = *(const floatx4*)(a1 + gk); x1 = *(const floatx4*)(a1 + gk + 4); }
                    if (aff_mode) {
                        #pragma unroll
                        for (int jj = 0; jj < 4; jj++) {
                            x0[jj] = fmaf(sc0[jj], x0[jj], sh0[jj]);
                            x1[jj] = fmaf(sc1[jj], x1[jj], sh1[jj]);
                        }
                    }
                    intx4 t = intx4{(int)bfpack2(x0[0], x0[1]), (int)bfpack2(x0[2], x0[3]),
                                    (int)bfpack2(x1[0], x1[1]), (int)bfpack2(x1[2], x1[3])};
                    af1 = *(bhalf8*)&t;
                }
            }
            #pragma unroll
            for (int j = 0; j < NT; j++) {
                acc[0][j] = __builtin_amdgcn_mfma_f32_16x16x32_bf16(af0, bf[j], acc[0][j], 0, 0, 0);
                acc[1][j] = __builtin_amdgcn_mfma_f32_16x16x32_bf16(af1, bf[j], acc[1][j], 0, 0, 0);
            }
        }
    }

    // epilogue
    float psum[NT], psq[NT];
    #pragma unroll
    for (int j = 0; j < NT; j++) { psum[j] = 0.f; psq[j] = 0.f; }

    #pragma unroll
    for (int j = 0; j < NT; j++) {
        int c = j * 16 + tl;
        float bv = (bias && c < Nact) ? bias[c] : 0.f;
        float rsc = 1.f, rsh = 0.f;
        if (res && res_stats && c < Nact) {
            float mu = res_stats[c] * INV_N;
            float var = res_stats[128 + c] * INV_N - mu * mu;
            rsc = res_g[c] * rsqrtf(var + BN_EPS);
            rsh = res_b[c] - mu * rsc;
        }
        #pragma unroll
        for (int t2 = 0; t2 < 2; t2++) {
            #pragma unroll
            for (int reg = 0; reg < 4; reg++) {
                int r = row0 + wave * 32 + t2 * 16 + q * 4 + reg;
                if (r >= M) continue;
                float v = 0.f;
                if (c < Nact) {
                    v = acc[t2][j][reg] + bv;
                    if (res) v += fmaf(rsc, res[(size_t)r * ldres + c], rsh - rsh + (res_stats ? rsh : 0.f));
                    if (relu) v = fmaxf(v, 0.f);
                    if (out_stats) { psum[j] += v; psq[j] = fmaf(v, v, psq[j]); }
                }
                if (Cbf) Cbf[(size_t)r * ldc + c] = bf16of(v);
                else     C  [(size_t)r * ldc + c] = v;
            }
        }
    }

    if (out_stats) {
        __syncthreads();
        if (tid < 128) { sc_s[tid] = 0.f; sh_s[tid] = 0.f; }
        __syncthreads();
        #pragma unroll
        for (int j = 0; j < NT; j++) {
            int c = j * 16 + tl;
            if (c < 128) { atomicAdd(&sc_s[c], psum[j]); atomicAdd(&sh_s[c], psq[j]); }
        }
        __syncthreads();
        if (tid < 128) {
            atomicAdd(&out_stats[tid], sc_s[tid]);
            atomicAdd(&out_stats[128 + tid], sh_s[tid]);
        }
    }
}

// ---------------------------------------------------------------- GAT pieces
__global__ void eler_kernel(const unsigned short* __restrict__ feat,
                            const float* __restrict__ al, const float* __restrict__ ar,
                            float* __restrict__ el, float* __restrict__ er) {
    int i = blockIdx.x * blockDim.x + threadIdx.x;
    if (i >= N_NODES * HEADS) return;
    int n = i >> 3, h = i & 7;
    const unsigned short* f = feat + (size_t)n * DIM + h * DHEAD;
    intx4 u0 = *(const intx4*)f;
    intx4 u1 = *(const intx4*)(f + 8);
    float sl = 0.f, sr = 0.f;
    const float* alh = al + h * DHEAD;
    const float* arh = ar + h * DHEAD;
    #pragma unroll
    for (int w = 0; w < 4; w++) {
        unsigned uw = (unsigned)u0[w];
        float flo = __uint_as_float(uw << 16);
        float fhi = __uint_as_float(uw & 0xFFFF0000u);
        sl = fmaf(flo, alh[2 * w], sl);     sr = fmaf(flo, arh[2 * w], sr);
        sl = fmaf(fhi, alh[2 * w + 1], sl); sr = fmaf(fhi, arh[2 * w + 1], sr);
    }
    #pragma unroll
    for (int w = 0; w < 4; w++) {
        unsigned uw = (unsigned)u1[w];
        float flo = __uint_as_float(uw << 16);
        float fhi = __uint_as_float(uw & 0xFFFF0000u);
        sl = fmaf(flo, alh[8 + 2 * w], sl);     sr = fmaf(flo, arh[8 + 2 * w], sr);
        sl = fmaf(fhi, alh[8 + 2 * w + 1], sl); sr = fmaf(fhi, arh[8 + 2 * w + 1], sr);
    }
    el[i] = sl;
    er[i] = sr;
}

__global__ void edge_exp_kernel(const int* __restrict__ srcs_csr,
                                const int* __restrict__ dsts_csr,
                                const float* __restrict__ el, const float* __restrict__ er,
                                float* __restrict__ ebuf_csr) {
    int i = blockIdx.x * blockDim.x + threadIdx.x;
    if (i >= N_EDGES) return;
    int s = srcs_csr[i], d = dsts_csr[i];
    floatx4 l0 = *(const floatx4*)&el[(size_t)s * 8];
    floatx4 l1 = *(const floatx4*)&el[(size_t)s * 8 + 4];
    floatx4 r0 = *(const floatx4*)&er[(size_t)d * 8];
    floatx4 r1 = *(const floatx4*)&er[(size_t)d * 8 + 4];
    floatx4 o0, o1;
    #pragma unroll
    for (int h = 0; h < 4; h++) {
        float v = l0[h] + r0[h];
        v = v > 0.f ? v : NEG_SLOPE * v;
        o0[h] = expf(v);
        float w = l1[h] + r1[h];
        w = w > 0.f ? w : NEG_SLOPE * w;
        o1[h] = expf(w);
    }
    *(floatx4*)&ebuf_csr[(size_t)i * 8]     = o0;
    *(floatx4*)&ebuf_csr[(size_t)i * 8 + 4] = o1;
}

// single-phase: denominator + weighted sum in one pass; h_in read with optional BN2 affine
__global__ __launch_bounds__(256) void gat_aggregate_kernel(
    const unsigned short* __restrict__ feat, const float* __restrict__ ebuf_csr,
    const int* __restrict__ indptr, const int* __restrict__ srcs_csr,
    const float* __restrict__ h_in, int ldh,
    const float* __restrict__ hstats, const float* __restrict__ hg,
    const float* __restrict__ hb,
    const float* __restrict__ bias,
    float* __restrict__ outp)
{
    int n = blockIdx.x;
    int t = threadIdx.x;
    __shared__ float red[256];
    __shared__ float den_s[2];
    int beg = indptr[n], end = indptr[n + 1];

    int p = t >> 7;
    int d = t & 127;
    int hh = d >> 4;
    float acc = 0.f, den = 0.f;
    int i = beg + p;
    for (; i + 6 < end; i += 8) {
        int s0 = srcs_csr[i],     s1 = srcs_csr[i + 2];
        int s2 = srcs_csr[i + 4], s3 = srcs_csr[i + 6];
        float a0 = ebuf_csr[(size_t)(i)     * HEADS + hh];
        float a1 = ebuf_csr[(size_t)(i + 2) * HEADS + hh];
        float a2 = ebuf_csr[(size_t)(i + 4) * HEADS + hh];
        float a3 = ebuf_csr[(size_t)(i + 6) * HEADS + hh];
        float f0 = bf2f(feat[(size_t)s0 * DIM + d]);
        float f1 = bf2f(feat[(size_t)s1 * DIM + d]);
        float f2 = bf2f(feat[(size_t)s2 * DIM + d]);
        float f3 = bf2f(feat[(size_t)s3 * DIM + d]);
        den += (a0 + a1) + (a2 + a3);
        acc = fmaf(a0, f0, acc);
        acc = fmaf(a1, f1, acc);
        acc = fmaf(a2, f2, acc);
        acc = fmaf(a3, f3, acc);
    }
    for (; i < end; i += 2) {
        int s0 = srcs_csr[i];
        float a0 = ebuf_csr[(size_t)i * HEADS + hh];
        den += a0;
        acc = fmaf(a0, bf2f(feat[(size_t)s0 * DIM + d]), acc);
    }
    red[t] = acc;
    if ((t & 127) == 0) den_s[p] = den;   // den identical across the group's threads... per-head? no: den is per-head!
    __syncthreads();
    if (t < 128) {
        // NOTE: den differs per head; recompute per-head denominators via red trick is wrong.
        // den for head hh computed by every thread of that head in each group; but den_s only
        // kept one head. Fix: use per-head den storage below.
    }
    __syncthreads();
    // correct per-head denominator: store one den per (group, head) pair
    __shared__ float denh[2][HEADS];
    if ((t & 15) == 0) denh[p][hh] = den;
    __syncthreads();
    if (t < 128) {
        float tot = red[d] + red[128 + d];
        float dtot = denh[0][hh] + denh[1][hh];
        float inv = dtot > 0.f ? 1.f / dtot : 0.f;
        float hv = h_in[(size_t)n * ldh + d];
        if (hstats) {
            float mu = hstats[d] * INV_N;
            float var = hstats[128 + d] * INV_N - mu * mu;
            float s = hg[d] * rsqrtf(var + BN_EPS);
            hv = fmaf(s, hv - mu, hb[d]);
        }
        outp[(size_t)n * DIM + d] = hv + tot * inv + bias[d];
    }
}

// ---------------------------------------------------------------- BN1 stats (only remaining stats pass)
__global__ __launch_bounds__(128) void bn_stats_kernel(const float* __restrict__ x, int ldx,
                                                       int M, float* __restrict__ stats) {
    int c = threadIdx.x;
    int r0 = blockIdx.x * 128;
    int r1 = min(r0 + 128, M);
    float s = 0.f, sq = 0.f;
    for (int r = r0; r < r1; r++) {
        float v = x[(size_t)r * ldx + c];
        s += v;
        sq = fmaf(v, v, sq);
    }
    atomicAdd(&stats[c], s);
    atomicAdd(&stats[DIM + c], sq);
}

// ---------------------------------------------------------------- decision head
__global__ __launch_bounds__(256) void decide_kernel(
    const float* __restrict__ z, const float* __restrict__ stats,
    const float* __restrict__ g, const float* __restrict__ b,
    const float* __restrict__ W2, float* __restrict__ outp, int M)
{
    int wid = threadIdx.x >> 6, lane = threadIdx.x & 63;
    int n = blockIdx.x * 4 + wid;
    if (n >= M) return;
    float acc = 0.f;
    for (int c = lane; c < DIM; c += 64) {
        float mu  = stats[c] * INV_N;
        float var = stats[DIM + c] * INV_N - mu * mu;
        float v = fmaf(g[c] * rsqrtf(var + BN_EPS), z[(size_t)n * DIM + c] - mu, b[c]);
        v = fmaxf(v, 0.f);
        acc = fmaf(v, W2[c], acc);
    }
    #pragma unroll
    for (int offs = 32; offs > 0; offs >>= 1)
        acc += __shfl_down(acc, offs);
    if (lane == 0) outp[n] = acc;
}

// ---------------------------------------------------------------- launch
extern "C" void kernel_launch(void* const* d_in, const int* in_sizes, int n_in,
                              void* d_out, int out_size, void* d_ws, size_t ws_size,
                              hipStream_t stream)
{
    const float* x      = (const float*)d_in[0];
    const int*   src    = (const int*)  d_in[1];
    const int*   dst    = (const int*)  d_in[2];
    const float* W_emb  = (const float*)d_in[3];
    const float* b_emb  = (const float*)d_in[4];
    const float* gat_W  = (const float*)d_in[5];
    const float* attn_l = (const float*)d_in[6];
    const float* attn_r = (const float*)d_in[7];
    const float* gat_b  = (const float*)d_in[8];
    const float* bn1_g  = (const float*)d_in[9];
    const float* bn1_b  = (const float*)d_in[10];
    const float* ff_W1  = (const float*)d_in[11];
    const float* ff_b1  = (const float*)d_in[12];
    const float* ff_W2  = (const float*)d_in[13];
    const float* ff_b2  = (const float*)d_in[14];
    const float* bn2_g  = (const float*)d_in[15];
    const float* bn2_b  = (const float*)d_in[16];
    const float* dec_W1 = (const float*)d_in[17];
    const float* dec_bn_g = (const float*)d_in[18];
    const float* dec_bn_b = (const float*)d_in[19];
    const float* dec_W2 = (const float*)d_in[20];
    float* outp = (float*)d_out;

    char* ws = (char*)d_ws;
    size_t off = 0;
    auto alloc = [&](size_t bytes) -> void* {
        void* p = ws + off;
        off += (bytes + 255) & ~(size_t)255;
        return p;
    };
    float* xs    = (float*)alloc((size_t)N_NODES * 512 * 4);       // [emb | t1 | t2 | t3] (t = pre-BN2)
    float* z     = (float*)alloc((size_t)N_NODES * DIM * 4);
    unsigned short* featb = (unsigned short*)alloc((size_t)N_NODES * DIM * 2);
    float* el    = (float*)alloc((size_t)N_NODES * HEADS * 4);
    float* er    = (float*)alloc((size_t)N_NODES * HEADS * 4);
    float* ebuf  = (float*)alloc((size_t)N_EDGES * HEADS * 4);
    unsigned short* y1b = (unsigned short*)alloc((size_t)N_NODES * 224 * 2);
    float* bt    = (float*)alloc((size_t)N_NODES * DIM * 4);       // pre-BN1 (agg out)
    int*   counts= (int*)  alloc((size_t)N_NODES * 4);             // contiguous with statsAll
    float* statsAll = (float*)alloc(7 * 256 * 4);                  // bn1[3] | bn2[3] | dec
    int*   indptr= (int*)  alloc((size_t)(N_NODES + 1) * 4);
    int*   cursor= (int*)  alloc((size_t)N_NODES * 4);
    int*   srcs_csr = (int*)alloc((size_t)N_EDGES * 4);
    int*   dsts_csr = (int*)alloc((size_t)N_EDGES * 4);
    (void)ws_size; (void)in_sizes; (void)n_in; (void)out_size;

    float* stats1 = statsAll;            // + l*256
    float* stats2 = statsAll + 3 * 256;  // + l*256
    float* statsD = statsAll + 6 * 256;

    int gemm_grid = (N_NODES + 127) / 128;

    // ---- one memset zeroes counts + all stats (contiguous allocs, both 256B-multiples)
    hipMemsetAsync(counts, 0, (size_t)N_NODES * 4 + 7 * 256 * 4, stream);
    hist_kernel<<<(N_EDGES + 255) / 256, 256, 0, stream>>>(dst, counts);
    scan_kernel<<<1, 1024, 0, stream>>>(counts, indptr, cursor, N_NODES);
    scatter_kernel<<<(N_EDGES + 255) / 256, 256, 0, stream>>>(src, dst, cursor, srcs_csr, dsts_csr);

    // ---- embed: xs[:,0:128] = x @ W_emb + b_emb
    gemm_bres_kernel<8, false><<<gemm_grid, 256, 0, stream>>>(
        x, nullptr, IN_DIM, W_emb, DIM, b_emb,
        nullptr, 0, nullptr, nullptr, nullptr,
        xs, nullptr, 512, nullptr,
        N_NODES, DIM, IN_DIM, 0, 0, nullptr, nullptr, nullptr);

    for (int l = 0; l < LAYERS; l++) {
        const float* h_cur = xs + (size_t)l * DIM;
        const float* hstats = l ? stats2 + (l - 1) * 256 : nullptr;
        const float* hg = l ? bn2_g + (l - 1) * DIM : nullptr;
        const float* hb = l ? bn2_b + (l - 1) * DIM : nullptr;
        // feat = BN2(h) @ gat_W  -> bf16
        gemm_bres_kernel<8, false><<<gemm_grid, 256, 0, stream>>>(
            h_cur, nullptr, 512, gat_W + (size_t)l * DIM * DIM, DIM, nullptr,
            nullptr, 0, nullptr, nullptr, nullptr,
            nullptr, featb, DIM, nullptr,
            N_NODES, DIM, DIM, 0, l ? 1 : 0, hstats, hg, hb);
        eler_kernel<<<(N_NODES * HEADS + 255) / 256, 256, 0, stream>>>(
            featb, attn_l + l * DIM, attn_r + l * DIM, el, er);
        edge_exp_kernel<<<(N_EDGES + 255) / 256, 256, 0, stream>>>(
            srcs_csr, dsts_csr, el, er, ebuf);
        // bt = BN2(h) + agg + bias   (pre-BN1)
        gat_aggregate_kernel<<<N_NODES, 256, 0, stream>>>(
            featb, ebuf, indptr, srcs_csr, h_cur, 512,
            hstats, hg, hb, gat_b + l * DIM, bt);
        // BN1 stats over bt
        bn_stats_kernel<<<(N_NODES + 127) / 128, 128, 0, stream>>>(
            bt, DIM, N_NODES, stats1 + l * 256);
        // FFN1: y1 = relu(BN1(bt) @ W1 + b1) -> bf16, ld224, pad zero-filled
        gemm_bres_kernel<14, false><<<gemm_grid, 256, 0, stream>>>(
            bt, nullptr, DIM, ff_W1 + (size_t)l * DIM * FF_DIM, FF_DIM,
            ff_b1 + l * FF_DIM,
            nullptr, 0, nullptr, nullptr, nullptr,
            nullptr, y1b, 224, nullptr,
            N_NODES, FF_DIM, DIM, 1,
            1, stats1 + l * 256, bn1_g + l * DIM, bn1_b + l * DIM);
        // FFN2: t = y1 @ W2 + b2 + BN1(bt) -> xs block l+1 (fp32) + bn2 stats
        gemm_bres_kernel<8, true><<<gemm_grid, 256, 0, stream>>>(
            nullptr, y1b, 224, ff_W2 + (size_t)l * FF_DIM * DIM, DIM,
            ff_b2 + l * DIM,
            bt, DIM, stats1 + l * 256, bn1_g + l * DIM, bn1_b + l * DIM,
            xs + (size_t)(l + 1) * DIM, nullptr, 512, stats2 + l * 256,
            N_NODES, DIM, FF_DIM, 0, 0, nullptr, nullptr, nullptr);
    }

    // ---- decision head: z = BN-affine-concat(xs) @ dec_W1 + dec stats
    gemm_bres_kernel<8, false><<<gemm_grid, 256, 0, stream>>>(
        xs, nullptr, 512, dec_W1, DIM, nullptr,
        nullptr, 0, nullptr, nullptr, nullptr,
        z, nullptr, DIM, statsD,
        N_NODES, DIM, 4 * DIM, 0, 2, stats2, bn2_g, bn2_b);
    decide_kernel<<<(N_NODES + 3) / 4, 256, 0, stream>>>(
        z, statsD, dec_bn_g, dec_bn_b, dec_W2, outp, N_NODES);
}

// Round 7
// 1014.439 us; speedup vs baseline: 1.1870x; 1.1147x over previous
//
#include <hip/hip_runtime.h>
#include <hip/hip_bf16.h>
#include <math.h>

#define N_NODES 40000
#define N_EDGES 640000
#define DIM     128
#define HEADS   8
#define DHEAD   16
#define LAYERS  3
#define IN_DIM  64
#define FF_DIM  218
#define BN_EPS  1e-5f
#define NEG_SLOPE 0.2f
#define INV_N   (1.f / N_NODES)

typedef __attribute__((ext_vector_type(8))) short  bhalf8;
typedef __attribute__((ext_vector_type(4))) float  floatx4;
typedef __attribute__((ext_vector_type(4))) int    intx4;

__device__ __forceinline__ unsigned bfpack2(float a, float b) {
    unsigned ua = __float_as_uint(a);
    ua = ua + 0x7FFFu + ((ua >> 16) & 1u);
    unsigned ub = __float_as_uint(b);
    ub = ub + 0x7FFFu + ((ub >> 16) & 1u);
    return (ua >> 16) | (ub & 0xFFFF0000u);
}
__device__ __forceinline__ unsigned short bf16of(float a) {
    unsigned ua = __float_as_uint(a);
    ua = ua + 0x7FFFu + ((ua >> 16) & 1u);
    return (unsigned short)(ua >> 16);
}
__device__ __forceinline__ float bf2f(unsigned short u) {
    unsigned v = ((unsigned)u) << 16;
    return __uint_as_float(v);
}

// packed weight layout offsets (bf16 elements)
#define OFF_EMB 0
#define OFF_GAT 8192
#define OFF_W1  57344
#define OFF_W2  143360
#define OFF_DEC 229376
#define WPK_TOT 294912

// ---------------------------------------------------------------- weight pre-pack
// all weights -> bf16 [n][kpad] row-major (B-fragment friendly)
__global__ void pack_weights_kernel(const float* __restrict__ W_emb,
                                    const float* __restrict__ gat_W,
                                    const float* __restrict__ ff_W1,
                                    const float* __restrict__ ff_W2,
                                    const float* __restrict__ dec_W1,
                                    unsigned short* __restrict__ wpk) {
    int i = blockIdx.x * 256 + threadIdx.x;
    if (i >= WPK_TOT) return;
    int o = i;
    if (o < 8192) {                       // emb: [128][64] <- W_emb[64][128]
        int n = o >> 6, k = o & 63;
        wpk[OFF_EMB + o] = bf16of(W_emb[k * 128 + n]);
        return;
    }
    o -= 8192;
    if (o < 3 * 16384) {                  // gat: [l][128][128] <- gat_W[l][128][128]
        int l = o >> 14, r = o & 16383;
        int n = r >> 7, k = r & 127;
        wpk[OFF_GAT + o] = bf16of(gat_W[l * 16384 + k * 128 + n]);
        return;
    }
    o -= 3 * 16384;
    if (o < 3 * 28672) {                  // W1: [l][224][128] <- ff_W1[l][128][218]
        int l = o / 28672, r = o % 28672;
        int n = r >> 7, k = r & 127;
        float v = (n < FF_DIM) ? ff_W1[(size_t)l * 128 * FF_DIM + k * FF_DIM + n] : 0.f;
        wpk[OFF_W1 + o] = bf16of(v);
        return;
    }
    o -= 3 * 28672;
    if (o < 3 * 28672) {                  // W2: [l][128][224] <- ff_W2[l][218][128]
        int l = o / 28672, r = o % 28672;
        int n = r / 224, k = r % 224;
        float v = (k < FF_DIM) ? ff_W2[(size_t)l * FF_DIM * 128 + k * 128 + n] : 0.f;
        wpk[OFF_W2 + o] = bf16of(v);
        return;
    }
    o -= 3 * 28672;
    {                                     // dec: [128][512] <- dec_W1[512][128]
        int n = o >> 9, k = o & 511;
        wpk[OFF_DEC + o] = bf16of(dec_W1[k * 128 + n]);
    }
}

// ---------------------------------------------------------------- CSR build
__global__ void hist_kernel(const int* __restrict__ dst, int* __restrict__ counts) {
    int e = blockIdx.x * blockDim.x + threadIdx.x;
    if (e < N_EDGES) atomicAdd(&counts[dst[e]], 1);
}

__global__ __launch_bounds__(1024) void scan_kernel(const int* __restrict__ counts,
                                                    int* __restrict__ indptr,
                                                    int* __restrict__ cursor, int n) {
    __shared__ int tsum[1024];
    const int CH = 40;
    int tid = threadIdx.x;
    int base = tid * CH;
    int loc[CH];
    int s = 0;
    #pragma unroll
    for (int i = 0; i < CH; i++) {
        int idx = base + i;
        int v = (idx < n) ? counts[idx] : 0;
        loc[i] = s;
        s += v;
    }
    tsum[tid] = s;
    __syncthreads();
    for (int offs = 1; offs < 1024; offs <<= 1) {
        int t = (tid >= offs) ? tsum[tid - offs] : 0;
        __syncthreads();
        tsum[tid] += t;
        __syncthreads();
    }
    int carry = (tid > 0) ? tsum[tid - 1] : 0;
    #pragma unroll
    for (int i = 0; i < CH; i++) {
        int idx = base + i;
        if (idx < n) {
            int v = carry + loc[i];
            indptr[idx] = v;
            cursor[idx] = v;
        }
    }
    if (tid == 1023) indptr[n] = tsum[1023];
}

__global__ void scatter_kernel(const int* __restrict__ src, const int* __restrict__ dst,
                               int* __restrict__ cursor,
                               int* __restrict__ srcs_csr, int* __restrict__ dsts_csr) {
    int e = blockIdx.x * blockDim.x + threadIdx.x;
    if (e < N_EDGES) {
        int d = dst[e];
        int pos = atomicAdd(&cursor[d], 1);
        srcs_csr[pos] = src[e];
        dsts_csr[pos] = d;
    }
}

// ---------------------------------------------------------------- L2-resident-B GEMM
// wave = 16 rows x NT*16 cols; grid = (ceil(M/64), col_groups); no B staging, no barriers
// in the K loop. B pre-packed bf16 [n][kpad]. Fusions: A-affine (BN), residual+BN epilogue,
// column stats, bf16 or fp32 out.
// aff_mode: 0 none; 1 simple (K<=512); 2 dec512 (block0 identity, blocks 1..3 BN2 affine)
template<int NT, bool ABF16>
__global__ __launch_bounds__(256) void gemm_l2_kernel(
    const float* __restrict__ A, const unsigned short* __restrict__ Abf, int lda,
    const unsigned short* __restrict__ Bpk, int kpad,
    const float* __restrict__ bias,
    const float* __restrict__ res, int ldres,
    const float* __restrict__ res_stats, const float* __restrict__ res_g,
    const float* __restrict__ res_b,
    float* __restrict__ C, unsigned short* __restrict__ Cbf, int ldc,
    float* __restrict__ out_stats,
    int M, int Nact, int relu,
    int aff_mode, const float* __restrict__ a_stats,
    const float* __restrict__ a_g, const float* __restrict__ a_b)
{
    __shared__ float sc_s[512];
    __shared__ float sh_s[512];

    int tid = threadIdx.x, wave = tid >> 6, lane = tid & 63;
    int q = lane >> 4, tl = lane & 15;
    int colbase = blockIdx.y * (NT * 16);
    int rowtile = blockIdx.x * 64 + wave * 16;
    int row = rowtile + tl;
    bool vr = row < M;

    if (aff_mode) {
        for (int idx = tid; idx < kpad; idx += 256) {
            float scv = 1.f, shv = 0.f;
            if (aff_mode == 1) {
                float mu = a_stats[idx] * INV_N;
                float var = a_stats[128 + idx] * INV_N - mu * mu;
                scv = a_g[idx] * rsqrtf(var + BN_EPS);
                shv = a_b[idx] - mu * scv;
            } else {
                int l = idx >> 7;
                if (l > 0) {
                    int c = idx & 127;
                    const float* st = a_stats + (l - 1) * 256;
                    float mu = st[c] * INV_N;
                    float var = st[128 + c] * INV_N - mu * mu;
                    scv = a_g[(l - 1) * 128 + c] * rsqrtf(var + BN_EPS);
                    shv = a_b[(l - 1) * 128 + c] - mu * scv;
                }
            }
            sc_s[idx] = scv;
            sh_s[idx] = shv;
        }
        __syncthreads();
    }

    const float* ap = ABF16 ? nullptr : A + (size_t)row * lda;
    const unsigned short* apb = ABF16 ? Abf + (size_t)row * lda : nullptr;
    const unsigned short* bp = Bpk + (size_t)colbase * kpad;

    floatx4 acc[NT] = {};

    for (int gk0 = 0; gk0 < kpad; gk0 += 32) {
        int gk = gk0 + q * 8;
        bhalf8 af = {};
        if constexpr (ABF16) {
            if (vr) af = *(const bhalf8*)(apb + gk);
        } else {
            floatx4 x0 = {}, x1 = {};
            if (vr) { x0 = *(const floatx4*)(ap + gk); x1 = *(const floatx4*)(ap + gk + 4); }
            if (aff_mode) {
                floatx4 sc0 = *(floatx4*)&sc_s[gk], sc1 = *(floatx4*)&sc_s[gk + 4];
                floatx4 sh0 = *(floatx4*)&sh_s[gk], sh1 = *(floatx4*)&sh_s[gk + 4];
                #pragma unroll
                for (int jj = 0; jj < 4; jj++) {
                    x0[jj] = fmaf(sc0[jj], x0[jj], sh0[jj]);
                    x1[jj] = fmaf(sc1[jj], x1[jj], sh1[jj]);
                }
            }
            intx4 t = intx4{(int)bfpack2(x0[0], x0[1]), (int)bfpack2(x0[2], x0[3]),
                            (int)bfpack2(x1[0], x1[1]), (int)bfpack2(x1[2], x1[3])};
            af = *(bhalf8*)&t;
        }
        bhalf8 bf[NT];
        #pragma unroll
        for (int j = 0; j < NT; j++)
            bf[j] = *(const bhalf8*)(bp + (size_t)(j * 16 + tl) * kpad + gk);
        #pragma unroll
        for (int j = 0; j < NT; j++)
            acc[j] = __builtin_amdgcn_mfma_f32_16x16x32_bf16(af, bf[j], acc[j], 0, 0, 0);
    }

    // epilogue: C/D layout col=lane&15, row=quad*4+reg
    float psum[NT], psq[NT];
    #pragma unroll
    for (int j = 0; j < NT; j++) { psum[j] = 0.f; psq[j] = 0.f; }

    #pragma unroll
    for (int j = 0; j < NT; j++) {
        int c = colbase + j * 16 + tl;
        bool cok = c < Nact;
        float bv = (bias && cok) ? bias[c] : 0.f;
        float rsc = 1.f, rsh = 0.f;
        if (res_stats && cok) {
            float mu = res_stats[c] * INV_N;
            float var = res_stats[128 + c] * INV_N - mu * mu;
            rsc = res_g[c] * rsqrtf(var + BN_EPS);
            rsh = res_b[c] - mu * rsc;
        }
        #pragma unroll
        for (int reg = 0; reg < 4; reg++) {
            int r = rowtile + q * 4 + reg;
            if (r >= M) continue;
            float v = 0.f;
            if (cok) {
                v = acc[j][reg] + bv;
                if (res) v = fmaf(rsc, res[(size_t)r * ldres + c], v + rsh);
                if (relu) v = fmaxf(v, 0.f);
                if (out_stats) { psum[j] += v; psq[j] = fmaf(v, v, psq[j]); }
            }
            if (Cbf) Cbf[(size_t)r * ldc + c] = bf16of(v);
            else     C  [(size_t)r * ldc + c] = v;
        }
    }

    if (out_stats) {
        __syncthreads();
        if (tid < 128) { sc_s[tid] = 0.f; sh_s[tid] = 0.f; }
        __syncthreads();
        #pragma unroll
        for (int j = 0; j < NT; j++) {
            int c = colbase + j * 16 + tl;
            if (c < 128) { atomicAdd(&sc_s[c], psum[j]); atomicAdd(&sh_s[c], psq[j]); }
        }
        __syncthreads();
        if (tid < 128) {
            atomicAdd(&out_stats[tid], sc_s[tid]);
            atomicAdd(&out_stats[128 + tid], sh_s[tid]);
        }
    }
}

// ---------------------------------------------------------------- GAT pieces
__global__ void eler_kernel(const unsigned short* __restrict__ feat,
                            const float* __restrict__ al, const float* __restrict__ ar,
                            float* __restrict__ el, float* __restrict__ er) {
    int i = blockIdx.x * blockDim.x + threadIdx.x;
    if (i >= N_NODES * HEADS) return;
    int n = i >> 3, h = i & 7;
    const unsigned short* f = feat + (size_t)n * DIM + h * DHEAD;
    intx4 u0 = *(const intx4*)f;
    intx4 u1 = *(const intx4*)(f + 8);
    float sl = 0.f, sr = 0.f;
    const float* alh = al + h * DHEAD;
    const float* arh = ar + h * DHEAD;
    #pragma unroll
    for (int w = 0; w < 4; w++) {
        unsigned uw = (unsigned)u0[w];
        float flo = __uint_as_float(uw << 16);
        float fhi = __uint_as_float(uw & 0xFFFF0000u);
        sl = fmaf(flo, alh[2 * w], sl);     sr = fmaf(flo, arh[2 * w], sr);
        sl = fmaf(fhi, alh[2 * w + 1], sl); sr = fmaf(fhi, arh[2 * w + 1], sr);
    }
    #pragma unroll
    for (int w = 0; w < 4; w++) {
        unsigned uw = (unsigned)u1[w];
        float flo = __uint_as_float(uw << 16);
        float fhi = __uint_as_float(uw & 0xFFFF0000u);
        sl = fmaf(flo, alh[8 + 2 * w], sl);     sr = fmaf(flo, arh[8 + 2 * w], sr);
        sl = fmaf(fhi, alh[8 + 2 * w + 1], sl); sr = fmaf(fhi, arh[8 + 2 * w + 1], sr);
    }
    el[i] = sl;
    er[i] = sr;
}

__global__ void edge_exp_kernel(const int* __restrict__ srcs_csr,
                                const int* __restrict__ dsts_csr,
                                const float* __restrict__ el, const float* __restrict__ er,
                                float* __restrict__ ebuf_csr) {
    int i = blockIdx.x * blockDim.x + threadIdx.x;
    if (i >= N_EDGES) return;
    int s = srcs_csr[i], d = dsts_csr[i];
    floatx4 l0 = *(const floatx4*)&el[(size_t)s * 8];
    floatx4 l1 = *(const floatx4*)&el[(size_t)s * 8 + 4];
    floatx4 r0 = *(const floatx4*)&er[(size_t)d * 8];
    floatx4 r1 = *(const floatx4*)&er[(size_t)d * 8 + 4];
    floatx4 o0, o1;
    #pragma unroll
    for (int h = 0; h < 4; h++) {
        float v = l0[h] + r0[h];
        v = v > 0.f ? v : NEG_SLOPE * v;
        o0[h] = expf(v);
        float w = l1[h] + r1[h];
        w = w > 0.f ? w : NEG_SLOPE * w;
        o1[h] = expf(w);
    }
    *(floatx4*)&ebuf_csr[(size_t)i * 8]     = o0;
    *(floatx4*)&ebuf_csr[(size_t)i * 8 + 4] = o1;
}

// single-phase softmax-aggregate; h_in with optional BN2 affine
__global__ __launch_bounds__(256) void gat_aggregate_kernel(
    const unsigned short* __restrict__ feat, const float* __restrict__ ebuf_csr,
    const int* __restrict__ indptr, const int* __restrict__ srcs_csr,
    const float* __restrict__ h_in, int ldh,
    const float* __restrict__ hstats, const float* __restrict__ hg,
    const float* __restrict__ hb,
    const float* __restrict__ bias,
    float* __restrict__ outp)
{
    int n = blockIdx.x;
    int t = threadIdx.x;
    __shared__ float red[256];
    __shared__ float denh[2][HEADS];
    int beg = indptr[n], end = indptr[n + 1];

    int p = t >> 7;
    int d = t & 127;
    int hh = d >> 4;
    float acc = 0.f, den = 0.f;
    int i = beg + p;
    for (; i + 6 < end; i += 8) {
        int s0 = srcs_csr[i],     s1 = srcs_csr[i + 2];
        int s2 = srcs_csr[i + 4], s3 = srcs_csr[i + 6];
        float a0 = ebuf_csr[(size_t)(i)     * HEADS + hh];
        float a1 = ebuf_csr[(size_t)(i + 2) * HEADS + hh];
        float a2 = ebuf_csr[(size_t)(i + 4) * HEADS + hh];
        float a3 = ebuf_csr[(size_t)(i + 6) * HEADS + hh];
        float f0 = bf2f(feat[(size_t)s0 * DIM + d]);
        float f1 = bf2f(feat[(size_t)s1 * DIM + d]);
        float f2 = bf2f(feat[(size_t)s2 * DIM + d]);
        float f3 = bf2f(feat[(size_t)s3 * DIM + d]);
        den += (a0 + a1) + (a2 + a3);
        acc = fmaf(a0, f0, acc);
        acc = fmaf(a1, f1, acc);
        acc = fmaf(a2, f2, acc);
        acc = fmaf(a3, f3, acc);
    }
    for (; i < end; i += 2) {
        int s0 = srcs_csr[i];
        float a0 = ebuf_csr[(size_t)i * HEADS + hh];
        den += a0;
        acc = fmaf(a0, bf2f(feat[(size_t)s0 * DIM + d]), acc);
    }
    red[t] = acc;
    if ((t & 15) == 0) denh[p][hh] = den;
    __syncthreads();
    if (t < 128) {
        float tot = red[d] + red[128 + d];
        float dtot = denh[0][hh] + denh[1][hh];
        float inv = dtot > 0.f ? 1.f / dtot : 0.f;
        float hv = h_in[(size_t)n * ldh + d];
        if (hstats) {
            float mu = hstats[d] * INV_N;
            float var = hstats[128 + d] * INV_N - mu * mu;
            float s = hg[d] * rsqrtf(var + BN_EPS);
            hv = fmaf(s, hv - mu, hb[d]);
        }
        outp[(size_t)n * DIM + d] = hv + tot * inv + bias[d];
    }
}

// ---------------------------------------------------------------- BN1 stats
__global__ __launch_bounds__(128) void bn_stats_kernel(const float* __restrict__ x, int ldx,
                                                       int M, float* __restrict__ stats) {
    int c = threadIdx.x;
    int r0 = blockIdx.x * 128;
    int r1 = min(r0 + 128, M);
    float s = 0.f, sq = 0.f;
    for (int r = r0; r < r1; r++) {
        float v = x[(size_t)r * ldx + c];
        s += v;
        sq = fmaf(v, v, sq);
    }
    atomicAdd(&stats[c], s);
    atomicAdd(&stats[DIM + c], sq);
}

// ---------------------------------------------------------------- decision head
__global__ __launch_bounds__(256) void decide_kernel(
    const float* __restrict__ z, const float* __restrict__ stats,
    const float* __restrict__ g, const float* __restrict__ b,
    const float* __restrict__ W2, float* __restrict__ outp, int M)
{
    int wid = threadIdx.x >> 6, lane = threadIdx.x & 63;
    int n = blockIdx.x * 4 + wid;
    if (n >= M) return;
    float acc = 0.f;
    for (int c = lane; c < DIM; c += 64) {
        float mu  = stats[c] * INV_N;
        float var = stats[DIM + c] * INV_N - mu * mu;
        float v = fmaf(g[c] * rsqrtf(var + BN_EPS), z[(size_t)n * DIM + c] - mu, b[c]);
        v = fmaxf(v, 0.f);
        acc = fmaf(v, W2[c], acc);
    }
    #pragma unroll
    for (int offs = 32; offs > 0; offs >>= 1)
        acc += __shfl_down(acc, offs);
    if (lane == 0) outp[n] = acc;
}

// ---------------------------------------------------------------- launch
extern "C" void kernel_launch(void* const* d_in, const int* in_sizes, int n_in,
                              void* d_out, int out_size, void* d_ws, size_t ws_size,
                              hipStream_t stream)
{
    const float* x      = (const float*)d_in[0];
    const int*   src    = (const int*)  d_in[1];
    const int*   dst    = (const int*)  d_in[2];
    const float* W_emb  = (const float*)d_in[3];
    const float* b_emb  = (const float*)d_in[4];
    const float* gat_W  = (const float*)d_in[5];
    const float* attn_l = (const float*)d_in[6];
    const float* attn_r = (const float*)d_in[7];
    const float* gat_b  = (const float*)d_in[8];
    const float* bn1_g  = (const float*)d_in[9];
    const float* bn1_b  = (const float*)d_in[10];
    const float* ff_W1  = (const float*)d_in[11];
    const float* ff_b1  = (const float*)d_in[12];
    const float* ff_W2  = (const float*)d_in[13];
    const float* ff_b2  = (const float*)d_in[14];
    const float* bn2_g  = (const float*)d_in[15];
    const float* bn2_b  = (const float*)d_in[16];
    const float* dec_W1 = (const float*)d_in[17];
    const float* dec_bn_g = (const float*)d_in[18];
    const float* dec_bn_b = (const float*)d_in[19];
    const float* dec_W2 = (const float*)d_in[20];
    float* outp = (float*)d_out;

    char* ws = (char*)d_ws;
    size_t off = 0;
    auto alloc = [&](size_t bytes) -> void* {
        void* p = ws + off;
        off += (bytes + 255) & ~(size_t)255;
        return p;
    };
    float* xs    = (float*)alloc((size_t)N_NODES * 512 * 4);   // [emb | t1 | t2 | t3] (t = pre-BN2)
    float* z     = (float*)alloc((size_t)N_NODES * DIM * 4);
    unsigned short* featb = (unsigned short*)alloc((size_t)N_NODES * DIM * 2);
    float* el    = (float*)alloc((size_t)N_NODES * HEADS * 4);
    float* er    = (float*)alloc((size_t)N_NODES * HEADS * 4);
    float* ebuf  = (float*)alloc((size_t)N_EDGES * HEADS * 4);
    unsigned short* y1b = (unsigned short*)alloc((size_t)N_NODES * 224 * 2);
    float* bt    = (float*)alloc((size_t)N_NODES * DIM * 4);   // pre-BN1 (agg out)
    int*   counts= (int*)  alloc((size_t)N_NODES * 4);         // contiguous with statsAll
    float* statsAll = (float*)alloc(7 * 256 * 4);              // bn1[3] | bn2[3] | dec
    unsigned short* wpk = (unsigned short*)alloc((size_t)WPK_TOT * 2);
    int*   indptr= (int*)  alloc((size_t)(N_NODES + 1) * 4);
    int*   cursor= (int*)  alloc((size_t)N_NODES * 4);
    int*   srcs_csr = (int*)alloc((size_t)N_EDGES * 4);
    int*   dsts_csr = (int*)alloc((size_t)N_EDGES * 4);
    (void)ws_size; (void)in_sizes; (void)n_in; (void)out_size;

    float* stats1 = statsAll;            // + l*256
    float* stats2 = statsAll + 3 * 256;  // + l*256
    float* statsD = statsAll + 6 * 256;

    dim3 gg((N_NODES + 63) / 64, 2);     // 625 x 2 col-groups

    // ---- memset (counts + all stats), CSR build, weight pack
    hipMemsetAsync(counts, 0, (size_t)N_NODES * 4 + 7 * 256 * 4, stream);
    hist_kernel<<<(N_EDGES + 255) / 256, 256, 0, stream>>>(dst, counts);
    scan_kernel<<<1, 1024, 0, stream>>>(counts, indptr, cursor, N_NODES);
    scatter_kernel<<<(N_EDGES + 255) / 256, 256, 0, stream>>>(src, dst, cursor, srcs_csr, dsts_csr);
    pack_weights_kernel<<<(WPK_TOT + 255) / 256, 256, 0, stream>>>(
        W_emb, gat_W, ff_W1, ff_W2, dec_W1, wpk);

    // ---- embed: xs[:,0:128] = x @ W_emb + b_emb
    gemm_l2_kernel<4, false><<<gg, 256, 0, stream>>>(
        x, nullptr, IN_DIM, wpk + OFF_EMB, 64, b_emb,
        nullptr, 0, nullptr, nullptr, nullptr,
        xs, nullptr, 512, nullptr,
        N_NODES, DIM, 0, 0, nullptr, nullptr, nullptr);

    for (int l = 0; l < LAYERS; l++) {
        const float* h_cur = xs + (size_t)l * DIM;
        const float* hstats = l ? stats2 + (l - 1) * 256 : nullptr;
        const float* hg = l ? bn2_g + (l - 1) * DIM : nullptr;
        const float* hb = l ? bn2_b + (l - 1) * DIM : nullptr;
        // feat = BN2(h) @ gat_W -> bf16
        gemm_l2_kernel<4, false><<<gg, 256, 0, stream>>>(
            h_cur, nullptr, 512, wpk + OFF_GAT + l * 16384, 128, nullptr,
            nullptr, 0, nullptr, nullptr, nullptr,
            nullptr, featb, DIM, nullptr,
            N_NODES, DIM, 0, l ? 1 : 0, hstats, hg, hb);
        eler_kernel<<<(N_NODES * HEADS + 255) / 256, 256, 0, stream>>>(
            featb, attn_l + l * DIM, attn_r + l * DIM, el, er);
        edge_exp_kernel<<<(N_EDGES + 255) / 256, 256, 0, stream>>>(
            srcs_csr, dsts_csr, el, er, ebuf);
        // bt = BN2(h) + agg + bias  (pre-BN1)
        gat_aggregate_kernel<<<N_NODES, 256, 0, stream>>>(
            featb, ebuf, indptr, srcs_csr, h_cur, 512,
            hstats, hg, hb, gat_b + l * DIM, bt);
        bn_stats_kernel<<<(N_NODES + 127) / 128, 128, 0, stream>>>(
            bt, DIM, N_NODES, stats1 + l * 256);
        // FFN1: y1 = relu(BN1(bt) @ W1 + b1) -> bf16 ld224 (pad zeroed)
        gemm_l2_kernel<7, false><<<gg, 256, 0, stream>>>(
            bt, nullptr, DIM, wpk + OFF_W1 + l * 28672, 128,
            ff_b1 + l * FF_DIM,
            nullptr, 0, nullptr, nullptr, nullptr,
            nullptr, y1b, 224, nullptr,
            N_NODES, FF_DIM, 1,
            1, stats1 + l * 256, bn1_g + l * DIM, bn1_b + l * DIM);
        // FFN2: t = y1 @ W2 + b2 + BN1(bt) -> xs block l+1 + bn2 stats
        gemm_l2_kernel<4, true><<<gg, 256, 0, stream>>>(
            nullptr, y1b, 224, wpk + OFF_W2 + l * 28672, 224,
            ff_b2 + l * DIM,
            bt, DIM, stats1 + l * 256, bn1_g + l * DIM, bn1_b + l * DIM,
            xs + (size_t)(l + 1) * DIM, nullptr, 512, stats2 + l * 256,
            N_NODES, DIM, 0, 0, nullptr, nullptr, nullptr);
    }

    // ---- decision head: z = BN-affine-concat(xs) @ dec_W1 + dec stats
    gemm_l2_kernel<4, false><<<gg, 256, 0, stream>>>(
        xs, nullptr, 512, wpk + OFF_DEC, 512, nullptr,
        nullptr, 0, nullptr, nullptr, nullptr,
        z, nullptr, DIM, statsD,
        N_NODES, DIM, 0, 2, stats2, bn2_g, bn2_b);
    decide_kernel<<<(N_NODES + 3) / 4, 256, 0, stream>>>(
        z, statsD, dec_bn_g, dec_bn_b, dec_W2, outp, N_NODES);
}

// Round 8
// 1001.493 us; speedup vs baseline: 1.2023x; 1.0129x over previous
//
#include <hip/hip_runtime.h>
#include <hip/hip_bf16.h>
#include <math.h>

#define N_NODES 40000
#define N_EDGES 640000
#define DIM     128
#define HEADS   8
#define DHEAD   16
#define LAYERS  3
#define IN_DIM  64
#define FF_DIM  218
#define BN_EPS  1e-5f
#define NEG_SLOPE 0.2f
#define INV_N   (1.f / N_NODES)

typedef __attribute__((ext_vector_type(8))) short  bhalf8;
typedef __attribute__((ext_vector_type(4))) float  floatx4;
typedef __attribute__((ext_vector_type(4))) int    intx4;

__device__ __forceinline__ unsigned bfpack2(float a, float b) {
    unsigned ua = __float_as_uint(a);
    ua = ua + 0x7FFFu + ((ua >> 16) & 1u);
    unsigned ub = __float_as_uint(b);
    ub = ub + 0x7FFFu + ((ub >> 16) & 1u);
    return (ua >> 16) | (ub & 0xFFFF0000u);
}
__device__ __forceinline__ unsigned short bf16of(float a) {
    unsigned ua = __float_as_uint(a);
    ua = ua + 0x7FFFu + ((ua >> 16) & 1u);
    return (unsigned short)(ua >> 16);
}
__device__ __forceinline__ float bf2f(unsigned short u) {
    return __uint_as_float(((unsigned)u) << 16);
}
__device__ __forceinline__ float bflo(unsigned u) { return __uint_as_float(u << 16); }
__device__ __forceinline__ float bfhi(unsigned u) { return __uint_as_float(u & 0xFFFF0000u); }

// packed weight layout offsets (bf16 elements)
#define OFF_EMB 0
#define OFF_GAT 8192
#define OFF_W1  57344
#define OFF_W2  143360
#define OFF_DEC 229376
#define WPK_TOT 294912

// ---------------------------------------------------------------- weight pre-pack
__global__ void pack_weights_kernel(const float* __restrict__ W_emb,
                                    const float* __restrict__ gat_W,
                                    const float* __restrict__ ff_W1,
                                    const float* __restrict__ ff_W2,
                                    const float* __restrict__ dec_W1,
                                    unsigned short* __restrict__ wpk) {
    int i = blockIdx.x * 256 + threadIdx.x;
    if (i >= WPK_TOT) return;
    int o = i;
    if (o < 8192) {                       // emb: [128][64]
        int n = o >> 6, k = o & 63;
        wpk[OFF_EMB + o] = bf16of(W_emb[k * 128 + n]);
        return;
    }
    o -= 8192;
    if (o < 3 * 16384) {                  // gat: [l][128][128]
        int l = o >> 14, r = o & 16383;
        int n = r >> 7, k = r & 127;
        wpk[OFF_GAT + o] = bf16of(gat_W[l * 16384 + k * 128 + n]);
        return;
    }
    o -= 3 * 16384;
    if (o < 3 * 28672) {                  // W1: [l][224][128]
        int l = o / 28672, r = o % 28672;
        int n = r >> 7, k = r & 127;
        float v = (n < FF_DIM) ? ff_W1[(size_t)l * 128 * FF_DIM + k * FF_DIM + n] : 0.f;
        wpk[OFF_W1 + o] = bf16of(v);
        return;
    }
    o -= 3 * 28672;
    if (o < 3 * 28672) {                  // W2: [l][128][224]
        int l = o / 28672, r = o % 28672;
        int n = r / 224, k = r % 224;
        float v = (k < FF_DIM) ? ff_W2[(size_t)l * FF_DIM * 128 + k * 128 + n] : 0.f;
        wpk[OFF_W2 + o] = bf16of(v);
        return;
    }
    o -= 3 * 28672;
    {                                     // dec: [128][512]
        int n = o >> 9, k = o & 511;
        wpk[OFF_DEC + o] = bf16of(dec_W1[k * 128 + n]);
    }
}

// ---------------------------------------------------------------- CSR build
__global__ void hist_kernel(const int* __restrict__ dst, int* __restrict__ counts) {
    int e = blockIdx.x * blockDim.x + threadIdx.x;
    if (e < N_EDGES) atomicAdd(&counts[dst[e]], 1);
}

__global__ __launch_bounds__(1024) void scan_kernel(const int* __restrict__ counts,
                                                    int* __restrict__ indptr,
                                                    int* __restrict__ cursor, int n) {
    __shared__ int tsum[1024];
    const int CH = 40;
    int tid = threadIdx.x;
    int base = tid * CH;
    int loc[CH];
    int s = 0;
    #pragma unroll
    for (int i = 0; i < CH; i++) {
        int idx = base + i;
        int v = (idx < n) ? counts[idx] : 0;
        loc[i] = s;
        s += v;
    }
    tsum[tid] = s;
    __syncthreads();
    for (int offs = 1; offs < 1024; offs <<= 1) {
        int t = (tid >= offs) ? tsum[tid - offs] : 0;
        __syncthreads();
        tsum[tid] += t;
        __syncthreads();
    }
    int carry = (tid > 0) ? tsum[tid - 1] : 0;
    #pragma unroll
    for (int i = 0; i < CH; i++) {
        int idx = base + i;
        if (idx < n) {
            int v = carry + loc[i];
            indptr[idx] = v;
            cursor[idx] = v;
        }
    }
    if (tid == 1023) indptr[n] = tsum[1023];
}

__global__ void scatter_kernel(const int* __restrict__ src, const int* __restrict__ dst,
                               int* __restrict__ cursor,
                               int* __restrict__ srcs_csr, int* __restrict__ dsts_csr) {
    int e = blockIdx.x * blockDim.x + threadIdx.x;
    if (e < N_EDGES) {
        int d = dst[e];
        int pos = atomicAdd(&cursor[d], 1);
        srcs_csr[pos] = src[e];
        dsts_csr[pos] = d;
    }
}

// ---------------------------------------------------------------- L2-resident-B GEMM
// Compile-time KPAD -> fully unrolled K loop; wave = 16 rows x NT*16 cols.
// AMODE: 0 none; 1 BN affine on A (K<=512, stats[128]); 2 dec512 layered affine.
template<int NT, int KPAD, int AMODE, bool ABF16>
__global__ __launch_bounds__(256) void gemm_l2_kernel(
    const float* __restrict__ A, const unsigned short* __restrict__ Abf, int lda,
    const unsigned short* __restrict__ Bpk,
    const float* __restrict__ bias,
    const float* __restrict__ res, int ldres,
    const float* __restrict__ res_stats, const float* __restrict__ res_g,
    const float* __restrict__ res_b,
    float* __restrict__ C, unsigned short* __restrict__ Cbf, int ldc,
    float* __restrict__ out_stats,
    int M, int Nact, int relu,
    const float* __restrict__ a_stats,
    const float* __restrict__ a_g, const float* __restrict__ a_b)
{
    constexpr int SCN = (AMODE > 0) ? KPAD : 1;
    __shared__ float sc_s[SCN];
    __shared__ float sh_s[SCN];
    __shared__ float st_sum[128];
    __shared__ float st_sq[128];

    int tid = threadIdx.x, wave = tid >> 6, lane = tid & 63;
    int q = lane >> 4, tl = lane & 15;
    int colbase = blockIdx.y * (NT * 16);
    int rowtile = blockIdx.x * 64 + wave * 16;
    int row = rowtile + tl;
    bool vr = row < M;

    if constexpr (AMODE > 0) {
        for (int idx = tid; idx < KPAD; idx += 256) {
            float scv = 1.f, shv = 0.f;
            if constexpr (AMODE == 1) {
                float mu = a_stats[idx] * INV_N;
                float var = a_stats[128 + idx] * INV_N - mu * mu;
                scv = a_g[idx] * rsqrtf(var + BN_EPS);
                shv = a_b[idx] - mu * scv;
            } else {
                int l = idx >> 7;
                if (l > 0) {
                    int c = idx & 127;
                    const float* st = a_stats + (l - 1) * 256;
                    float mu = st[c] * INV_N;
                    float var = st[128 + c] * INV_N - mu * mu;
                    scv = a_g[(l - 1) * 128 + c] * rsqrtf(var + BN_EPS);
                    shv = a_b[(l - 1) * 128 + c] - mu * scv;
                }
            }
            sc_s[idx] = scv;
            sh_s[idx] = shv;
        }
        __syncthreads();
    }

    const float* ap = ABF16 ? nullptr : A + (size_t)row * lda;
    const unsigned short* apb = ABF16 ? Abf + (size_t)row * lda : nullptr;
    const unsigned short* bp = Bpk + (size_t)colbase * KPAD;

    floatx4 acc[NT] = {};

    #pragma unroll
    for (int gk0 = 0; gk0 < KPAD; gk0 += 32) {
        int gk = gk0 + q * 8;
        bhalf8 af;
        if constexpr (ABF16) {
            intx4 u = {};
            if (vr) u = *(const intx4*)(apb + gk);
            if constexpr (AMODE > 0) {
                #pragma unroll
                for (int w = 0; w < 4; w++) {
                    unsigned uw = (unsigned)u[w];
                    float lo = bflo(uw), hi = bfhi(uw);
                    lo = fmaf(sc_s[gk + 2 * w],     lo, sh_s[gk + 2 * w]);
                    hi = fmaf(sc_s[gk + 2 * w + 1], hi, sh_s[gk + 2 * w + 1]);
                    u[w] = (int)bfpack2(lo, hi);
                }
            }
            af = *(bhalf8*)&u;
        } else {
            floatx4 x0 = {}, x1 = {};
            if (vr) { x0 = *(const floatx4*)(ap + gk); x1 = *(const floatx4*)(ap + gk + 4); }
            if constexpr (AMODE > 0) {
                #pragma unroll
                for (int jj = 0; jj < 4; jj++) {
                    x0[jj] = fmaf(sc_s[gk + jj],     x0[jj], sh_s[gk + jj]);
                    x1[jj] = fmaf(sc_s[gk + 4 + jj], x1[jj], sh_s[gk + 4 + jj]);
                }
            }
            intx4 t = intx4{(int)bfpack2(x0[0], x0[1]), (int)bfpack2(x0[2], x0[3]),
                            (int)bfpack2(x1[0], x1[1]), (int)bfpack2(x1[2], x1[3])};
            af = *(bhalf8*)&t;
        }
        bhalf8 bf[NT];
        #pragma unroll
        for (int j = 0; j < NT; j++)
            bf[j] = *(const bhalf8*)(bp + (size_t)(j * 16 + tl) * KPAD + gk);
        #pragma unroll
        for (int j = 0; j < NT; j++)
            acc[j] = __builtin_amdgcn_mfma_f32_16x16x32_bf16(af, bf[j], acc[j], 0, 0, 0);
    }

    // epilogue: C/D layout col=lane&15, row=quad*4+reg
    float psum[NT], psq[NT];
    #pragma unroll
    for (int j = 0; j < NT; j++) { psum[j] = 0.f; psq[j] = 0.f; }

    #pragma unroll
    for (int j = 0; j < NT; j++) {
        int c = colbase + j * 16 + tl;
        bool cok = c < Nact;
        float bv = (bias && cok) ? bias[c] : 0.f;
        float rsc = 1.f, rsh = 0.f;
        if (res_stats && cok) {
            float mu = res_stats[c] * INV_N;
            float var = res_stats[128 + c] * INV_N - mu * mu;
            rsc = res_g[c] * rsqrtf(var + BN_EPS);
            rsh = res_b[c] - mu * rsc;
        }
        #pragma unroll
        for (int reg = 0; reg < 4; reg++) {
            int r = rowtile + q * 4 + reg;
            if (r >= M) continue;
            float v = 0.f;
            if (cok) {
                v = acc[j][reg] + bv;
                if (res) v = fmaf(rsc, res[(size_t)r * ldres + c], v + rsh);
                if (relu) v = fmaxf(v, 0.f);
                if (out_stats) { psum[j] += v; psq[j] = fmaf(v, v, psq[j]); }
            }
            if (Cbf) Cbf[(size_t)r * ldc + c] = bf16of(v);
            else     C  [(size_t)r * ldc + c] = v;
        }
    }

    if (out_stats) {
        __syncthreads();
        if (tid < 128) { st_sum[tid] = 0.f; st_sq[tid] = 0.f; }
        __syncthreads();
        #pragma unroll
        for (int j = 0; j < NT; j++) {
            int c = colbase + j * 16 + tl;
            if (c < 128) { atomicAdd(&st_sum[c], psum[j]); atomicAdd(&st_sq[c], psq[j]); }
        }
        __syncthreads();
        if (tid < 128) {
            atomicAdd(&out_stats[tid], st_sum[tid]);
            atomicAdd(&out_stats[128 + tid], st_sq[tid]);
        }
    }
}

// ---------------------------------------------------------------- GAT pieces
__global__ void eler_kernel(const unsigned short* __restrict__ feat,
                            const float* __restrict__ al, const float* __restrict__ ar,
                            float* __restrict__ el, float* __restrict__ er) {
    int i = blockIdx.x * blockDim.x + threadIdx.x;
    if (i >= N_NODES * HEADS) return;
    int n = i >> 3, h = i & 7;
    const unsigned short* f = feat + (size_t)n * DIM + h * DHEAD;
    intx4 u0 = *(const intx4*)f;
    intx4 u1 = *(const intx4*)(f + 8);
    float sl = 0.f, sr = 0.f;
    const float* alh = al + h * DHEAD;
    const float* arh = ar + h * DHEAD;
    #pragma unroll
    for (int w = 0; w < 4; w++) {
        unsigned uw = (unsigned)u0[w];
        float flo = bflo(uw), fhi = bfhi(uw);
        sl = fmaf(flo, alh[2 * w], sl);     sr = fmaf(flo, arh[2 * w], sr);
        sl = fmaf(fhi, alh[2 * w + 1], sl); sr = fmaf(fhi, arh[2 * w + 1], sr);
    }
    #pragma unroll
    for (int w = 0; w < 4; w++) {
        unsigned uw = (unsigned)u1[w];
        float flo = bflo(uw), fhi = bfhi(uw);
        sl = fmaf(flo, alh[8 + 2 * w], sl);     sr = fmaf(flo, arh[8 + 2 * w], sr);
        sl = fmaf(fhi, alh[8 + 2 * w + 1], sl); sr = fmaf(fhi, arh[8 + 2 * w + 1], sr);
    }
    el[i] = sl;
    er[i] = sr;
}

__global__ void edge_exp_kernel(const int* __restrict__ srcs_csr,
                                const int* __restrict__ dsts_csr,
                                const float* __restrict__ el, const float* __restrict__ er,
                                float* __restrict__ ebuf_csr) {
    int i = blockIdx.x * blockDim.x + threadIdx.x;
    if (i >= N_EDGES) return;
    int s = srcs_csr[i], d = dsts_csr[i];
    floatx4 l0 = *(const floatx4*)&el[(size_t)s * 8];
    floatx4 l1 = *(const floatx4*)&el[(size_t)s * 8 + 4];
    floatx4 r0 = *(const floatx4*)&er[(size_t)d * 8];
    floatx4 r1 = *(const floatx4*)&er[(size_t)d * 8 + 4];
    floatx4 o0, o1;
    #pragma unroll
    for (int h = 0; h < 4; h++) {
        float v = l0[h] + r0[h];
        v = v > 0.f ? v : NEG_SLOPE * v;
        o0[h] = expf(v);
        float w = l1[h] + r1[h];
        w = w > 0.f ? w : NEG_SLOPE * w;
        o1[h] = expf(w);
    }
    *(floatx4*)&ebuf_csr[(size_t)i * 8]     = o0;
    *(floatx4*)&ebuf_csr[(size_t)i * 8 + 4] = o1;
}

// 4 edge-groups x 64 lanes; lane owns a dim-pair (dword loads); 4-way unroll
__global__ __launch_bounds__(256) void gat_aggregate_kernel(
    const unsigned short* __restrict__ feat, const float* __restrict__ ebuf_csr,
    const int* __restrict__ indptr, const int* __restrict__ srcs_csr,
    const unsigned short* __restrict__ h_in, int ldh,
    const float* __restrict__ hstats, const float* __restrict__ hg,
    const float* __restrict__ hb,
    const float* __restrict__ bias,
    float* __restrict__ outp)
{
    int n = blockIdx.x;
    int t = threadIdx.x;
    int p = t >> 6;            // group 0..3
    int lane = t & 63;         // dim pair index
    int d0 = lane * 2;
    int hh = lane >> 3;        // head
    __shared__ float red[4][128];
    __shared__ float denh[4][HEADS];
    int beg = indptr[n], end = indptr[n + 1];

    float acc0 = 0.f, acc1 = 0.f, den = 0.f;
    int i = beg + p;
    for (; i + 12 < end; i += 16) {
        int s0 = srcs_csr[i],     s1 = srcs_csr[i + 4];
        int s2 = srcs_csr[i + 8], s3 = srcs_csr[i + 12];
        float a0 = ebuf_csr[(size_t)(i)      * HEADS + hh];
        float a1 = ebuf_csr[(size_t)(i + 4)  * HEADS + hh];
        float a2 = ebuf_csr[(size_t)(i + 8)  * HEADS + hh];
        float a3 = ebuf_csr[(size_t)(i + 12) * HEADS + hh];
        unsigned f0 = *(const unsigned*)(feat + (size_t)s0 * DIM + d0);
        unsigned f1 = *(const unsigned*)(feat + (size_t)s1 * DIM + d0);
        unsigned f2 = *(const unsigned*)(feat + (size_t)s2 * DIM + d0);
        unsigned f3 = *(const unsigned*)(feat + (size_t)s3 * DIM + d0);
        den += (a0 + a1) + (a2 + a3);
        acc0 = fmaf(a0, bflo(f0), acc0); acc1 = fmaf(a0, bfhi(f0), acc1);
        acc0 = fmaf(a1, bflo(f1), acc0); acc1 = fmaf(a1, bfhi(f1), acc1);
        acc0 = fmaf(a2, bflo(f2), acc0); acc1 = fmaf(a2, bfhi(f2), acc1);
        acc0 = fmaf(a3, bflo(f3), acc0); acc1 = fmaf(a3, bfhi(f3), acc1);
    }
    for (; i < end; i += 4) {
        int s0 = srcs_csr[i];
        float a0 = ebuf_csr[(size_t)i * HEADS + hh];
        unsigned f0 = *(const unsigned*)(feat + (size_t)s0 * DIM + d0);
        den += a0;
        acc0 = fmaf(a0, bflo(f0), acc0);
        acc1 = fmaf(a0, bfhi(f0), acc1);
    }
    red[p][d0] = acc0;
    red[p][d0 + 1] = acc1;
    if ((lane & 7) == 0) denh[p][hh] = den;
    __syncthreads();
    if (t < 128) {
        int d = t, h = d >> 4;
        float tot = (red[0][d] + red[1][d]) + (red[2][d] + red[3][d]);
        float dtot = (denh[0][h] + denh[1][h]) + (denh[2][h] + denh[3][h]);
        float inv = dtot > 0.f ? 1.f / dtot : 0.f;
        float hv = bf2f(h_in[(size_t)n * ldh + d]);
        if (hstats) {
            float mu = hstats[d] * INV_N;
            float var = hstats[128 + d] * INV_N - mu * mu;
            float s = hg[d] * rsqrtf(var + BN_EPS);
            hv = fmaf(s, hv - mu, hb[d]);
        }
        outp[(size_t)n * DIM + d] = hv + tot * inv + bias[d];
    }
}

// ---------------------------------------------------------------- BN1 stats
__global__ __launch_bounds__(128) void bn_stats_kernel(const float* __restrict__ x, int ldx,
                                                       int M, float* __restrict__ stats) {
    int c = threadIdx.x;
    int r0 = blockIdx.x * 128;
    int r1 = min(r0 + 128, M);
    float s = 0.f, sq = 0.f;
    for (int r = r0; r < r1; r++) {
        float v = x[(size_t)r * ldx + c];
        s += v;
        sq = fmaf(v, v, sq);
    }
    atomicAdd(&stats[c], s);
    atomicAdd(&stats[DIM + c], sq);
}

// ---------------------------------------------------------------- decision head
__global__ __launch_bounds__(256) void decide_kernel(
    const float* __restrict__ z, const float* __restrict__ stats,
    const float* __restrict__ g, const float* __restrict__ b,
    const float* __restrict__ W2, float* __restrict__ outp, int M)
{
    int wid = threadIdx.x >> 6, lane = threadIdx.x & 63;
    int n = blockIdx.x * 4 + wid;
    if (n >= M) return;
    float acc = 0.f;
    for (int c = lane; c < DIM; c += 64) {
        float mu  = stats[c] * INV_N;
        float var = stats[DIM + c] * INV_N - mu * mu;
        float v = fmaf(g[c] * rsqrtf(var + BN_EPS), z[(size_t)n * DIM + c] - mu, b[c]);
        v = fmaxf(v, 0.f);
        acc = fmaf(v, W2[c], acc);
    }
    #pragma unroll
    for (int offs = 32; offs > 0; offs >>= 1)
        acc += __shfl_down(acc, offs);
    if (lane == 0) outp[n] = acc;
}

// ---------------------------------------------------------------- launch
extern "C" void kernel_launch(void* const* d_in, const int* in_sizes, int n_in,
                              void* d_out, int out_size, void* d_ws, size_t ws_size,
                              hipStream_t stream)
{
    const float* x      = (const float*)d_in[0];
    const int*   src    = (const int*)  d_in[1];
    const int*   dst    = (const int*)  d_in[2];
    const float* W_emb  = (const float*)d_in[3];
    const float* b_emb  = (const float*)d_in[4];
    const float* gat_W  = (const float*)d_in[5];
    const float* attn_l = (const float*)d_in[6];
    const float* attn_r = (const float*)d_in[7];
    const float* gat_b  = (const float*)d_in[8];
    const float* bn1_g  = (const float*)d_in[9];
    const float* bn1_b  = (const float*)d_in[10];
    const float* ff_W1  = (const float*)d_in[11];
    const float* ff_b1  = (const float*)d_in[12];
    const float* ff_W2  = (const float*)d_in[13];
    const float* ff_b2  = (const float*)d_in[14];
    const float* bn2_g  = (const float*)d_in[15];
    const float* bn2_b  = (const float*)d_in[16];
    const float* dec_W1 = (const float*)d_in[17];
    const float* dec_bn_g = (const float*)d_in[18];
    const float* dec_bn_b = (const float*)d_in[19];
    const float* dec_W2 = (const float*)d_in[20];
    float* outp = (float*)d_out;

    char* ws = (char*)d_ws;
    size_t off = 0;
    auto alloc = [&](size_t bytes) -> void* {
        void* p = ws + off;
        off += (bytes + 255) & ~(size_t)255;
        return p;
    };
    unsigned short* xsb = (unsigned short*)alloc((size_t)N_NODES * 512 * 2);  // bf16 [emb|t1|t2|t3]
    float* z     = (float*)alloc((size_t)N_NODES * DIM * 4);
    unsigned short* featb = (unsigned short*)alloc((size_t)N_NODES * DIM * 2);
    float* el    = (float*)alloc((size_t)N_NODES * HEADS * 4);
    float* er    = (float*)alloc((size_t)N_NODES * HEADS * 4);
    float* ebuf  = (float*)alloc((size_t)N_EDGES * HEADS * 4);
    unsigned short* y1b = (unsigned short*)alloc((size_t)N_NODES * 224 * 2);
    float* bt    = (float*)alloc((size_t)N_NODES * DIM * 4);
    int*   counts= (int*)  alloc((size_t)N_NODES * 4);          // contiguous with statsAll
    float* statsAll = (float*)alloc(7 * 256 * 4);
    unsigned short* wpk = (unsigned short*)alloc((size_t)WPK_TOT * 2);
    int*   indptr= (int*)  alloc((size_t)(N_NODES + 1) * 4);
    int*   cursor= (int*)  alloc((size_t)N_NODES * 4);
    int*   srcs_csr = (int*)alloc((size_t)N_EDGES * 4);
    int*   dsts_csr = (int*)alloc((size_t)N_EDGES * 4);
    (void)ws_size; (void)in_sizes; (void)n_in; (void)out_size;

    float* stats1 = statsAll;
    float* stats2 = statsAll + 3 * 256;
    float* statsD = statsAll + 6 * 256;

    dim3 gg((N_NODES + 63) / 64, 2);

    hipMemsetAsync(counts, 0, (size_t)N_NODES * 4 + 7 * 256 * 4, stream);
    hist_kernel<<<(N_EDGES + 255) / 256, 256, 0, stream>>>(dst, counts);
    scan_kernel<<<1, 1024, 0, stream>>>(counts, indptr, cursor, N_NODES);
    scatter_kernel<<<(N_EDGES + 255) / 256, 256, 0, stream>>>(src, dst, cursor, srcs_csr, dsts_csr);
    pack_weights_kernel<<<(WPK_TOT + 255) / 256, 256, 0, stream>>>(
        W_emb, gat_W, ff_W1, ff_W2, dec_W1, wpk);

    // embed: xsb[:,0:128] = x @ W_emb + b_emb   (fp32 A, K=64)
    gemm_l2_kernel<4, 64, 0, false><<<gg, 256, 0, stream>>>(
        x, nullptr, IN_DIM, wpk + OFF_EMB, b_emb,
        nullptr, 0, nullptr, nullptr, nullptr,
        nullptr, xsb, 512, nullptr,
        N_NODES, DIM, 0, nullptr, nullptr, nullptr);

    for (int l = 0; l < LAYERS; l++) {
        const unsigned short* h_cur = xsb + (size_t)l * DIM;
        const float* hstats = l ? stats2 + (l - 1) * 256 : nullptr;
        const float* hg = l ? bn2_g + (l - 1) * DIM : nullptr;
        const float* hb = l ? bn2_b + (l - 1) * DIM : nullptr;
        // feat = BN2(h) @ gat_W -> bf16
        if (l == 0)
            gemm_l2_kernel<4, 128, 0, true><<<gg, 256, 0, stream>>>(
                nullptr, h_cur, 512, wpk + OFF_GAT + l * 16384, nullptr,
                nullptr, 0, nullptr, nullptr, nullptr,
                nullptr, featb, DIM, nullptr,
                N_NODES, DIM, 0, nullptr, nullptr, nullptr);
        else
            gemm_l2_kernel<4, 128, 1, true><<<gg, 256, 0, stream>>>(
                nullptr, h_cur, 512, wpk + OFF_GAT + l * 16384, nullptr,
                nullptr, 0, nullptr, nullptr, nullptr,
                nullptr, featb, DIM, nullptr,
                N_NODES, DIM, 0, hstats, hg, hb);
        eler_kernel<<<(N_NODES * HEADS + 255) / 256, 256, 0, stream>>>(
            featb, attn_l + l * DIM, attn_r + l * DIM, el, er);
        edge_exp_kernel<<<(N_EDGES + 255) / 256, 256, 0, stream>>>(
            srcs_csr, dsts_csr, el, er, ebuf);
        // bt = BN2(h) + agg + bias  (pre-BN1, fp32)
        gat_aggregate_kernel<<<N_NODES, 256, 0, stream>>>(
            featb, ebuf, indptr, srcs_csr, h_cur, 512,
            hstats, hg, hb, gat_b + l * DIM, bt);
        bn_stats_kernel<<<(N_NODES + 127) / 128, 128, 0, stream>>>(
            bt, DIM, N_NODES, stats1 + l * 256);
        // FFN1: y1 = relu(BN1(bt) @ W1 + b1) -> bf16 ld224
        gemm_l2_kernel<7, 128, 1, false><<<gg, 256, 0, stream>>>(
            bt, nullptr, DIM, wpk + OFF_W1 + l * 28672,
            ff_b1 + l * FF_DIM,
            nullptr, 0, nullptr, nullptr, nullptr,
            nullptr, y1b, 224, nullptr,
            N_NODES, FF_DIM, 1,
            stats1 + l * 256, bn1_g + l * DIM, bn1_b + l * DIM);
        // FFN2: t = y1 @ W2 + b2 + BN1(bt) -> xsb block l+1 (bf16) + bn2 stats
        gemm_l2_kernel<4, 224, 0, true><<<gg, 256, 0, stream>>>(
            nullptr, y1b, 224, wpk + OFF_W2 + l * 28672,
            ff_b2 + l * DIM,
            bt, DIM, stats1 + l * 256, bn1_g + l * DIM, bn1_b + l * DIM,
            nullptr, xsb + (size_t)(l + 1) * DIM, 512, stats2 + l * 256,
            N_NODES, DIM, 0, nullptr, nullptr, nullptr);
    }

    // dec: z = BN-affine-concat(xsb) @ dec_W1 + dec stats
    gemm_l2_kernel<4, 512, 2, true><<<gg, 256, 0, stream>>>(
        nullptr, xsb, 512, wpk + OFF_DEC, nullptr,
        nullptr, 0, nullptr, nullptr, nullptr,
        z, nullptr, DIM, statsD,
        N_NODES, DIM, 0, stats2, bn2_g, bn2_b);
    decide_kernel<<<(N_NODES + 3) / 4, 256, 0, stream>>>(
        z, statsD, dec_bn_g, dec_bn_b, dec_W2, outp, N_NODES);
}

// Round 9
// 878.635 us; speedup vs baseline: 1.3704x; 1.1398x over previous
//
#include <hip/hip_runtime.h>
#include <hip/hip_bf16.h>
#include <math.h>

#define N_NODES 40000
#define N_EDGES 640000
#define DIM     128
#define HEADS   8
#define DHEAD   16
#define LAYERS  3
#define IN_DIM  64
#define FF_DIM  218
#define BN_EPS  1e-5f
#define NEG_SLOPE 0.2f
#define INV_N   (1.f / N_NODES)

typedef __attribute__((ext_vector_type(8))) short  bhalf8;
typedef __attribute__((ext_vector_type(4))) float  floatx4;
typedef __attribute__((ext_vector_type(4))) int    intx4;

__device__ __forceinline__ unsigned bfpack2(float a, float b) {
    unsigned ua = __float_as_uint(a);
    ua = ua + 0x7FFFu + ((ua >> 16) & 1u);
    unsigned ub = __float_as_uint(b);
    ub = ub + 0x7FFFu + ((ub >> 16) & 1u);
    return (ua >> 16) | (ub & 0xFFFF0000u);
}
__device__ __forceinline__ unsigned short bf16of(float a) {
    unsigned ua = __float_as_uint(a);
    ua = ua + 0x7FFFu + ((ua >> 16) & 1u);
    return (unsigned short)(ua >> 16);
}
__device__ __forceinline__ float bf2f(unsigned short u) {
    return __uint_as_float(((unsigned)u) << 16);
}
__device__ __forceinline__ float bflo(unsigned u) { return __uint_as_float(u << 16); }
__device__ __forceinline__ float bfhi(unsigned u) { return __uint_as_float(u & 0xFFFF0000u); }
__device__ __forceinline__ float rsum16(float v) {
    v += __shfl_xor(v, 1, 16);
    v += __shfl_xor(v, 2, 16);
    v += __shfl_xor(v, 4, 16);
    v += __shfl_xor(v, 8, 16);
    return v;
}

// packed weight layout offsets (bf16 elements)
#define OFF_EMB 0
#define OFF_GAT 8192
#define OFF_W1  57344
#define OFF_W2  143360
#define OFF_DEC 229376
#define WPK_TOT 294912

// ---------------------------------------------------------------- weight pre-pack
__global__ void pack_weights_kernel(const float* __restrict__ W_emb,
                                    const float* __restrict__ gat_W,
                                    const float* __restrict__ ff_W1,
                                    const float* __restrict__ ff_W2,
                                    const float* __restrict__ dec_W1,
                                    unsigned short* __restrict__ wpk) {
    int i = blockIdx.x * 256 + threadIdx.x;
    if (i >= WPK_TOT) return;
    int o = i;
    if (o < 8192) {                       // emb: [128][64]
        int n = o >> 6, k = o & 63;
        wpk[OFF_EMB + o] = bf16of(W_emb[k * 128 + n]);
        return;
    }
    o -= 8192;
    if (o < 3 * 16384) {                  // gat: [l][128][128]
        int l = o >> 14, r = o & 16383;
        int n = r >> 7, k = r & 127;
        wpk[OFF_GAT + o] = bf16of(gat_W[l * 16384 + k * 128 + n]);
        return;
    }
    o -= 3 * 16384;
    if (o < 3 * 28672) {                  // W1: [l][224][128]
        int l = o / 28672, r = o % 28672;
        int n = r >> 7, k = r & 127;
        float v = (n < FF_DIM) ? ff_W1[(size_t)l * 128 * FF_DIM + k * FF_DIM + n] : 0.f;
        wpk[OFF_W1 + o] = bf16of(v);
        return;
    }
    o -= 3 * 28672;
    if (o < 3 * 28672) {                  // W2: [l][128][224]
        int l = o / 28672, r = o % 28672;
        int n = r / 224, k = r % 224;
        float v = (k < FF_DIM) ? ff_W2[(size_t)l * FF_DIM * 128 + k * 128 + n] : 0.f;
        wpk[OFF_W2 + o] = bf16of(v);
        return;
    }
    o -= 3 * 28672;
    {                                     // dec: [128][512]
        int n = o >> 9, k = o & 511;
        wpk[OFF_DEC + o] = bf16of(dec_W1[k * 128 + n]);
    }
}

// ---------------------------------------------------------------- CSR build
__global__ void hist_kernel(const int* __restrict__ dst, int* __restrict__ counts) {
    int e = blockIdx.x * blockDim.x + threadIdx.x;
    if (e < N_EDGES) atomicAdd(&counts[dst[e]], 1);
}

__global__ __launch_bounds__(1024) void scan_kernel(const int* __restrict__ counts,
                                                    int* __restrict__ indptr,
                                                    int* __restrict__ cursor, int n) {
    __shared__ int tsum[1024];
    const int CH = 40;
    int tid = threadIdx.x;
    int base = tid * CH;
    int loc[CH];
    int s = 0;
    #pragma unroll
    for (int i = 0; i < CH; i++) {
        int idx = base + i;
        int v = (idx < n) ? counts[idx] : 0;
        loc[i] = s;
        s += v;
    }
    tsum[tid] = s;
    __syncthreads();
    for (int offs = 1; offs < 1024; offs <<= 1) {
        int t = (tid >= offs) ? tsum[tid - offs] : 0;
        __syncthreads();
        tsum[tid] += t;
        __syncthreads();
    }
    int carry = (tid > 0) ? tsum[tid - 1] : 0;
    #pragma unroll
    for (int i = 0; i < CH; i++) {
        int idx = base + i;
        if (idx < n) {
            int v = carry + loc[i];
            indptr[idx] = v;
            cursor[idx] = v;
        }
    }
    if (tid == 1023) indptr[n] = tsum[1023];
}

__global__ void scatter_kernel(const int* __restrict__ src, const int* __restrict__ dst,
                               int* __restrict__ cursor,
                               int* __restrict__ srcs_csr) {
    int e = blockIdx.x * blockDim.x + threadIdx.x;
    if (e < N_EDGES) {
        int d = dst[e];
        int pos = atomicAdd(&cursor[d], 1);
        srcs_csr[pos] = src[e];
    }
}

// ---------------------------------------------------------------- L2-resident-B GEMM
// wave = MT*16 rows x NT*16 cols; K fully unrolled (compile-time KPAD).
// AMODE: 0 none; 1 BN affine on A; 2 dec512 layered affine.
// ELER: fused el/er head-reduction (feat GEMM); col-group g owns heads 4g..4g+3.
template<int NT, int KPAD, int AMODE, bool ABF16, int MT, bool ELER>
__global__ __launch_bounds__(256) void gemm_l2_kernel(
    const float* __restrict__ A, const unsigned short* __restrict__ Abf, int lda,
    const unsigned short* __restrict__ Bpk,
    const float* __restrict__ bias,
    const float* __restrict__ res, int ldres,
    const float* __restrict__ res_stats, const float* __restrict__ res_g,
    const float* __restrict__ res_b,
    float* __restrict__ C, unsigned short* __restrict__ Cbf, int ldc,
    float* __restrict__ out_stats,
    int M, int Nact, int relu,
    const float* __restrict__ a_stats,
    const float* __restrict__ a_g, const float* __restrict__ a_b,
    const float* __restrict__ al, const float* __restrict__ ar,
    float* __restrict__ el_out, float* __restrict__ er_out)
{
    constexpr int SCN = (AMODE > 0) ? KPAD : 1;
    constexpr int BROWS = 64 * MT;
    __shared__ float sc_s[SCN];
    __shared__ float sh_s[SCN];
    __shared__ float st_sum[128];
    __shared__ float st_sq[128];
    __shared__ float el_s[ELER ? BROWS : 1][4];
    __shared__ float er_s[ELER ? BROWS : 1][4];

    int tid = threadIdx.x, wave = tid >> 6, lane = tid & 63;
    int q = lane >> 4, tl = lane & 15;
    int colbase = blockIdx.y * (NT * 16);
    int row0b = blockIdx.x * BROWS;
    int rowtile = row0b + wave * (MT * 16);

    if constexpr (AMODE > 0) {
        for (int idx = tid; idx < KPAD; idx += 256) {
            float scv = 1.f, shv = 0.f;
            if constexpr (AMODE == 1) {
                float mu = a_stats[idx] * INV_N;
                float var = a_stats[128 + idx] * INV_N - mu * mu;
                scv = a_g[idx] * rsqrtf(var + BN_EPS);
                shv = a_b[idx] - mu * scv;
            } else {
                int l = idx >> 7;
                if (l > 0) {
                    int c = idx & 127;
                    const float* st = a_stats + (l - 1) * 256;
                    float mu = st[c] * INV_N;
                    float var = st[128 + c] * INV_N - mu * mu;
                    scv = a_g[(l - 1) * 128 + c] * rsqrtf(var + BN_EPS);
                    shv = a_b[(l - 1) * 128 + c] - mu * scv;
                }
            }
            sc_s[idx] = scv;
            sh_s[idx] = shv;
        }
        __syncthreads();
    }

    int rowm[MT];
    bool vrm[MT];
    #pragma unroll
    for (int mt = 0; mt < MT; mt++) {
        rowm[mt] = rowtile + mt * 16 + tl;
        vrm[mt] = rowm[mt] < M;
    }
    const unsigned short* bp = Bpk + (size_t)colbase * KPAD;

    floatx4 acc[MT][NT] = {};

    #pragma unroll
    for (int gk0 = 0; gk0 < KPAD; gk0 += 32) {
        int gk = gk0 + q * 8;
        bhalf8 af[MT];
        #pragma unroll
        for (int mt = 0; mt < MT; mt++) {
            if constexpr (ABF16) {
                intx4 u = {};
                if (vrm[mt]) u = *(const intx4*)(Abf + (size_t)rowm[mt] * lda + gk);
                if constexpr (AMODE > 0) {
                    #pragma unroll
                    for (int w = 0; w < 4; w++) {
                        unsigned uw = (unsigned)u[w];
                        float lo = bflo(uw), hi = bfhi(uw);
                        lo = fmaf(sc_s[gk + 2 * w],     lo, sh_s[gk + 2 * w]);
                        hi = fmaf(sc_s[gk + 2 * w + 1], hi, sh_s[gk + 2 * w + 1]);
                        u[w] = (int)bfpack2(lo, hi);
                    }
                }
                af[mt] = *(bhalf8*)&u;
            } else {
                floatx4 x0 = {}, x1 = {};
                if (vrm[mt]) {
                    const float* ap = A + (size_t)rowm[mt] * lda + gk;
                    x0 = *(const floatx4*)ap;
                    x1 = *(const floatx4*)(ap + 4);
                }
                if constexpr (AMODE > 0) {
                    #pragma unroll
                    for (int jj = 0; jj < 4; jj++) {
                        x0[jj] = fmaf(sc_s[gk + jj],     x0[jj], sh_s[gk + jj]);
                        x1[jj] = fmaf(sc_s[gk + 4 + jj], x1[jj], sh_s[gk + 4 + jj]);
                    }
                }
                intx4 t = intx4{(int)bfpack2(x0[0], x0[1]), (int)bfpack2(x0[2], x0[3]),
                                (int)bfpack2(x1[0], x1[1]), (int)bfpack2(x1[2], x1[3])};
                af[mt] = *(bhalf8*)&t;
            }
        }
        bhalf8 bf[NT];
        #pragma unroll
        for (int j = 0; j < NT; j++)
            bf[j] = *(const bhalf8*)(bp + (size_t)(j * 16 + tl) * KPAD + gk);
        #pragma unroll
        for (int mt = 0; mt < MT; mt++)
            #pragma unroll
            for (int j = 0; j < NT; j++)
                acc[mt][j] = __builtin_amdgcn_mfma_f32_16x16x32_bf16(af[mt], bf[j], acc[mt][j], 0, 0, 0);
    }

    // epilogue: C/D layout col=lane&15, row=quad*4+reg
    float psum[NT], psq[NT];
    #pragma unroll
    for (int j = 0; j < NT; j++) { psum[j] = 0.f; psq[j] = 0.f; }

    #pragma unroll
    for (int j = 0; j < NT; j++) {
        int c = colbase + j * 16 + tl;
        bool cok = c < Nact;
        float bv = (bias && cok) ? bias[c] : 0.f;
        float rsc = 1.f, rsh = 0.f;
        if (res_stats && cok) {
            float mu = res_stats[c] * INV_N;
            float var = res_stats[128 + c] * INV_N - mu * mu;
            rsc = res_g[c] * rsqrtf(var + BN_EPS);
            rsh = res_b[c] - mu * rsc;
        }
        float alc = 0.f, arc = 0.f;
        if constexpr (ELER) { alc = al[c]; arc = ar[c]; }
        #pragma unroll
        for (int mt = 0; mt < MT; mt++) {
            #pragma unroll
            for (int reg = 0; reg < 4; reg++) {
                int r = rowtile + mt * 16 + q * 4 + reg;
                bool rok = r < M;
                float v = 0.f;
                if (rok && cok) {
                    v = acc[mt][j][reg] + bv;
                    if (res) v = fmaf(rsc, res[(size_t)r * ldres + c], v + rsh);
                    if (relu) v = fmaxf(v, 0.f);
                    if (out_stats) { psum[j] += v; psq[j] = fmaf(v, v, psq[j]); }
                }
                if constexpr (ELER) {
                    float pel = rsum16(v * alc);
                    float per_ = rsum16(v * arc);
                    if (tl == 0) {
                        int rl = wave * (MT * 16) + mt * 16 + q * 4 + reg;
                        el_s[rl][j] = pel;
                        er_s[rl][j] = per_;
                    }
                }
                if (rok && cok) {
                    if (Cbf) Cbf[(size_t)r * ldc + c] = bf16of(v);
                    else     C  [(size_t)r * ldc + c] = v;
                }
            }
        }
    }

    if constexpr (ELER) {
        __syncthreads();
        int g4 = blockIdx.y * 4;
        for (int idx = tid; idx < BROWS * 4; idx += 256) {
            int rl = idx >> 2, hj = idx & 3;
            int r = row0b + rl;
            if (r < M) {
                el_out[(size_t)r * 8 + g4 + hj] = el_s[rl][hj];
                er_out[(size_t)r * 8 + g4 + hj] = er_s[rl][hj];
            }
        }
    }

    if (out_stats) {
        __syncthreads();
        if (tid < 128) { st_sum[tid] = 0.f; st_sq[tid] = 0.f; }
        __syncthreads();
        #pragma unroll
        for (int j = 0; j < NT; j++) {
            int c = colbase + j * 16 + tl;
            if (c < 128) { atomicAdd(&st_sum[c], psum[j]); atomicAdd(&st_sq[c], psq[j]); }
        }
        __syncthreads();
        if (tid < 128) {
            atomicAdd(&out_stats[tid], st_sum[tid]);
            atomicAdd(&out_stats[128 + tid], st_sq[tid]);
        }
    }
}

// ---------------------------------------------------------------- GAT aggregate
// inline exp(leaky(el[src]+er[n])); 4 edge-groups x 64 lanes; lane owns a dim-pair
__global__ __launch_bounds__(256) void gat_aggregate_kernel(
    const unsigned short* __restrict__ feat,
    const float* __restrict__ el, const float* __restrict__ er,
    const int* __restrict__ indptr, const int* __restrict__ srcs_csr,
    const unsigned short* __restrict__ h_in, int ldh,
    const float* __restrict__ hstats, const float* __restrict__ hg,
    const float* __restrict__ hb,
    const float* __restrict__ bias,
    float* __restrict__ outp)
{
    int n = blockIdx.x;
    int t = threadIdx.x;
    int p = t >> 6;
    int lane = t & 63;
    int d0 = lane * 2;
    int hh = lane >> 3;
    __shared__ float red[4][128];
    __shared__ float denh[4][HEADS];
    int beg = indptr[n], end = indptr[n + 1];
    float ern = er[(size_t)n * 8 + hh];

    float acc0 = 0.f, acc1 = 0.f, den = 0.f;
    int i = beg + p;
    for (; i + 12 < end; i += 16) {
        int s0 = srcs_csr[i],     s1 = srcs_csr[i + 4];
        int s2 = srcs_csr[i + 8], s3 = srcs_csr[i + 12];
        float e0 = el[(size_t)s0 * 8 + hh] + ern;
        float e1 = el[(size_t)s1 * 8 + hh] + ern;
        float e2 = el[(size_t)s2 * 8 + hh] + ern;
        float e3 = el[(size_t)s3 * 8 + hh] + ern;
        unsigned f0 = *(const unsigned*)(feat + (size_t)s0 * DIM + d0);
        unsigned f1 = *(const unsigned*)(feat + (size_t)s1 * DIM + d0);
        unsigned f2 = *(const unsigned*)(feat + (size_t)s2 * DIM + d0);
        unsigned f3 = *(const unsigned*)(feat + (size_t)s3 * DIM + d0);
        float a0 = expf(e0 > 0.f ? e0 : NEG_SLOPE * e0);
        float a1 = expf(e1 > 0.f ? e1 : NEG_SLOPE * e1);
        float a2 = expf(e2 > 0.f ? e2 : NEG_SLOPE * e2);
        float a3 = expf(e3 > 0.f ? e3 : NEG_SLOPE * e3);
        den += (a0 + a1) + (a2 + a3);
        acc0 = fmaf(a0, bflo(f0), acc0); acc1 = fmaf(a0, bfhi(f0), acc1);
        acc0 = fmaf(a1, bflo(f1), acc0); acc1 = fmaf(a1, bfhi(f1), acc1);
        acc0 = fmaf(a2, bflo(f2), acc0); acc1 = fmaf(a2, bfhi(f2), acc1);
        acc0 = fmaf(a3, bflo(f3), acc0); acc1 = fmaf(a3, bfhi(f3), acc1);
    }
    for (; i < end; i += 4) {
        int s0 = srcs_csr[i];
        float e0 = el[(size_t)s0 * 8 + hh] + ern;
        unsigned f0 = *(const unsigned*)(feat + (size_t)s0 * DIM + d0);
        float a0 = expf(e0 > 0.f ? e0 : NEG_SLOPE * e0);
        den += a0;
        acc0 = fmaf(a0, bflo(f0), acc0);
        acc1 = fmaf(a0, bfhi(f0), acc1);
    }
    red[p][d0] = acc0;
    red[p][d0 + 1] = acc1;
    if ((lane & 7) == 0) denh[p][hh] = den;
    __syncthreads();
    if (t < 128) {
        int d = t, h = d >> 4;
        float tot = (red[0][d] + red[1][d]) + (red[2][d] + red[3][d]);
        float dtot = (denh[0][h] + denh[1][h]) + (denh[2][h] + denh[3][h]);
        float inv = dtot > 0.f ? 1.f / dtot : 0.f;
        float hv = bf2f(h_in[(size_t)n * ldh + d]);
        if (hstats) {
            float mu = hstats[d] * INV_N;
            float var = hstats[128 + d] * INV_N - mu * mu;
            float s = hg[d] * rsqrtf(var + BN_EPS);
            hv = fmaf(s, hv - mu, hb[d]);
        }
        outp[(size_t)n * DIM + d] = hv + tot * inv + bias[d];
    }
}

// ---------------------------------------------------------------- BN1 stats
__global__ __launch_bounds__(128) void bn_stats_kernel(const float* __restrict__ x, int ldx,
                                                       int M, float* __restrict__ stats) {
    int c = threadIdx.x;
    int r0 = blockIdx.x * 128;
    int r1 = min(r0 + 128, M);
    float s = 0.f, sq = 0.f;
    for (int r = r0; r < r1; r++) {
        float v = x[(size_t)r * ldx + c];
        s += v;
        sq = fmaf(v, v, sq);
    }
    atomicAdd(&stats[c], s);
    atomicAdd(&stats[DIM + c], sq);
}

// ---------------------------------------------------------------- decision head
__global__ __launch_bounds__(256) void decide_kernel(
    const unsigned short* __restrict__ z, const float* __restrict__ stats,
    const float* __restrict__ g, const float* __restrict__ b,
    const float* __restrict__ W2, float* __restrict__ outp, int M)
{
    int wid = threadIdx.x >> 6, lane = threadIdx.x & 63;
    int n = blockIdx.x * 4 + wid;
    if (n >= M) return;
    float acc = 0.f;
    #pragma unroll
    for (int cc = 0; cc < 2; cc++) {
        int c = lane + cc * 64;
        float mu  = stats[c] * INV_N;
        float var = stats[DIM + c] * INV_N - mu * mu;
        float v = fmaf(g[c] * rsqrtf(var + BN_EPS), bf2f(z[(size_t)n * DIM + c]) - mu, b[c]);
        v = fmaxf(v, 0.f);
        acc = fmaf(v, W2[c], acc);
    }
    #pragma unroll
    for (int offs = 32; offs > 0; offs >>= 1)
        acc += __shfl_down(acc, offs);
    if (lane == 0) outp[n] = acc;
}

// ---------------------------------------------------------------- launch
extern "C" void kernel_launch(void* const* d_in, const int* in_sizes, int n_in,
                              void* d_out, int out_size, void* d_ws, size_t ws_size,
                              hipStream_t stream)
{
    const float* x      = (const float*)d_in[0];
    const int*   src    = (const int*)  d_in[1];
    const int*   dst    = (const int*)  d_in[2];
    const float* W_emb  = (const float*)d_in[3];
    const float* b_emb  = (const float*)d_in[4];
    const float* gat_W  = (const float*)d_in[5];
    const float* attn_l = (const float*)d_in[6];
    const float* attn_r = (const float*)d_in[7];
    const float* gat_b  = (const float*)d_in[8];
    const float* bn1_g  = (const float*)d_in[9];
    const float* bn1_b  = (const float*)d_in[10];
    const float* ff_W1  = (const float*)d_in[11];
    const float* ff_b1  = (const float*)d_in[12];
    const float* ff_W2  = (const float*)d_in[13];
    const float* ff_b2  = (const float*)d_in[14];
    const float* bn2_g  = (const float*)d_in[15];
    const float* bn2_b  = (const float*)d_in[16];
    const float* dec_W1 = (const float*)d_in[17];
    const float* dec_bn_g = (const float*)d_in[18];
    const float* dec_bn_b = (const float*)d_in[19];
    const float* dec_W2 = (const float*)d_in[20];
    float* outp = (float*)d_out;

    char* ws = (char*)d_ws;
    size_t off = 0;
    auto alloc = [&](size_t bytes) -> void* {
        void* p = ws + off;
        off += (bytes + 255) & ~(size_t)255;
        return p;
    };
    unsigned short* xsb = (unsigned short*)alloc((size_t)N_NODES * 512 * 2);
    unsigned short* zb  = (unsigned short*)alloc((size_t)N_NODES * DIM * 2);
    unsigned short* featb = (unsigned short*)alloc((size_t)N_NODES * DIM * 2);
    float* el    = (float*)alloc((size_t)N_NODES * HEADS * 4);
    float* er    = (float*)alloc((size_t)N_NODES * HEADS * 4);
    unsigned short* y1b = (unsigned short*)alloc((size_t)N_NODES * 224 * 2);
    float* bt    = (float*)alloc((size_t)N_NODES * DIM * 4);
    int*   counts= (int*)  alloc((size_t)N_NODES * 4);          // contiguous with statsAll
    float* statsAll = (float*)alloc(7 * 256 * 4);
    unsigned short* wpk = (unsigned short*)alloc((size_t)WPK_TOT * 2);
    int*   indptr= (int*)  alloc((size_t)(N_NODES + 1) * 4);
    int*   cursor= (int*)  alloc((size_t)N_NODES * 4);
    int*   srcs_csr = (int*)alloc((size_t)N_EDGES * 4);
    (void)ws_size; (void)in_sizes; (void)n_in; (void)out_size;

    float* stats1 = statsAll;
    float* stats2 = statsAll + 3 * 256;
    float* statsD = statsAll + 6 * 256;

    dim3 gg((N_NODES + 127) / 128, 2);   // MT=2: 128 rows/block

    hipMemsetAsync(counts, 0, (size_t)N_NODES * 4 + 7 * 256 * 4, stream);
    hist_kernel<<<(N_EDGES + 255) / 256, 256, 0, stream>>>(dst, counts);
    scan_kernel<<<1, 1024, 0, stream>>>(counts, indptr, cursor, N_NODES);
    scatter_kernel<<<(N_EDGES + 255) / 256, 256, 0, stream>>>(src, dst, cursor, srcs_csr);
    pack_weights_kernel<<<(WPK_TOT + 255) / 256, 256, 0, stream>>>(
        W_emb, gat_W, ff_W1, ff_W2, dec_W1, wpk);

    // embed: xsb[:,0:128] = x @ W_emb + b_emb
    gemm_l2_kernel<4, 64, 0, false, 2, false><<<gg, 256, 0, stream>>>(
        x, nullptr, IN_DIM, wpk + OFF_EMB, b_emb,
        nullptr, 0, nullptr, nullptr, nullptr,
        nullptr, xsb, 512, nullptr,
        N_NODES, DIM, 0, nullptr, nullptr, nullptr,
        nullptr, nullptr, nullptr, nullptr);

    for (int l = 0; l < LAYERS; l++) {
        const unsigned short* h_cur = xsb + (size_t)l * DIM;
        const float* hstats = l ? stats2 + (l - 1) * 256 : nullptr;
        const float* hg = l ? bn2_g + (l - 1) * DIM : nullptr;
        const float* hb = l ? bn2_b + (l - 1) * DIM : nullptr;
        // feat = BN2(h) @ gat_W -> bf16, fused el/er
        if (l == 0)
            gemm_l2_kernel<4, 128, 0, true, 2, true><<<gg, 256, 0, stream>>>(
                nullptr, h_cur, 512, wpk + OFF_GAT + l * 16384, nullptr,
                nullptr, 0, nullptr, nullptr, nullptr,
                nullptr, featb, DIM, nullptr,
                N_NODES, DIM, 0, nullptr, nullptr, nullptr,
                attn_l + l * DIM, attn_r + l * DIM, el, er);
        else
            gemm_l2_kernel<4, 128, 1, true, 2, true><<<gg, 256, 0, stream>>>(
                nullptr, h_cur, 512, wpk + OFF_GAT + l * 16384, nullptr,
                nullptr, 0, nullptr, nullptr, nullptr,
                nullptr, featb, DIM, nullptr,
                N_NODES, DIM, 0, hstats, hg, hb,
                attn_l + l * DIM, attn_r + l * DIM, el, er);
        // bt = BN2(h) + agg + bias  (pre-BN1, fp32); inline edge exp
        gat_aggregate_kernel<<<N_NODES, 256, 0, stream>>>(
            featb, el, er, indptr, srcs_csr, h_cur, 512,
            hstats, hg, hb, gat_b + l * DIM, bt);
        bn_stats_kernel<<<(N_NODES + 127) / 128, 128, 0, stream>>>(
            bt, DIM, N_NODES, stats1 + l * 256);
        // FFN1: y1 = relu(BN1(bt) @ W1 + b1) -> bf16 ld224
        gemm_l2_kernel<7, 128, 1, false, 2, false><<<gg, 256, 0, stream>>>(
            bt, nullptr, DIM, wpk + OFF_W1 + l * 28672,
            ff_b1 + l * FF_DIM,
            nullptr, 0, nullptr, nullptr, nullptr,
            nullptr, y1b, 224, nullptr,
            N_NODES, FF_DIM, 1,
            stats1 + l * 256, bn1_g + l * DIM, bn1_b + l * DIM,
            nullptr, nullptr, nullptr, nullptr);
        // FFN2: t = y1 @ W2 + b2 + BN1(bt) -> xsb block l+1 (bf16) + bn2 stats
        gemm_l2_kernel<4, 224, 0, true, 2, false><<<gg, 256, 0, stream>>>(
            nullptr, y1b, 224, wpk + OFF_W2 + l * 28672,
            ff_b2 + l * DIM,
            bt, DIM, stats1 + l * 256, bn1_g + l * DIM, bn1_b + l * DIM,
            nullptr, xsb + (size_t)(l + 1) * DIM, 512, stats2 + l * 256,
            N_NODES, DIM, 0, nullptr, nullptr, nullptr,
            nullptr, nullptr, nullptr, nullptr);
    }

    // dec: z = BN-affine-concat(xsb) @ dec_W1 (bf16 out) + dec stats
    gemm_l2_kernel<4, 512, 2, true, 2, false><<<gg, 256, 0, stream>>>(
        nullptr, xsb, 512, wpk + OFF_DEC, nullptr,
        nullptr, 0, nullptr, nullptr, nullptr,
        nullptr, zb, DIM, statsD,
        N_NODES, DIM, 0, stats2, bn2_g, bn2_b,
        nullptr, nullptr, nullptr, nullptr);
    decide_kernel<<<(N_NODES + 3) / 4, 256, 0, stream>>>(
        zb, statsD, dec_bn_g, dec_bn_b, dec_W2, outp, N_NODES);
}